// Round 11
// baseline (1538.978 us; speedup 1.0000x reference)
//
#include <hip/hip_runtime.h>
#include <hip/hip_bf16.h>
#include <math.h>

#define N_    30000
#define E_    480000
#define C_    128
#define K_    8
#define L_    4
#define H_    256
#define NHID_ 512
#define NOUT_ 256
#define B_    1024
#define SCAN_B 30   // ceil(N_/1024)

typedef __attribute__((ext_vector_type(8))) short short8;
typedef __attribute__((ext_vector_type(4))) float floatx4;
typedef __hip_bfloat16 bf16;

static inline size_t align256(size_t x){ return (x + 255) & ~(size_t)255; }

__device__ __forceinline__ void gload_lds16(const void* g, void* l){
  __builtin_amdgcn_global_load_lds((const __attribute__((address_space(1))) void*)g,
                                   (__attribute__((address_space(3))) void*)l, 16, 0, 0);
}
__device__ __forceinline__ float bf2f(short s){
  union { unsigned u; float f; } x; x.u = ((unsigned)(unsigned short)s) << 16; return x.f;
}
// fast sigmoid/tanh: v_exp-based, ~1e-5 rel err (negligible vs bf16 rounding)
__device__ __forceinline__ float sigm_f(float x){ return __builtin_amdgcn_rcpf(1.f + __expf(-x)); }
__device__ __forceinline__ float tanh_f(float x){ return 1.f - 2.f*__builtin_amdgcn_rcpf(1.f + __expf(2.f*x)); }

// ============================ CSR build ============================
__global__ void hist_k(const int* __restrict__ dst, int* __restrict__ cnt){
  int e = blockIdx.x*256 + threadIdx.x;
  if (e < E_) atomicAdd(&cnt[dst[e]], 1);
}

__global__ void scan1_k(const int* __restrict__ cnt, int* __restrict__ rowptr, int* __restrict__ btot){
  __shared__ int sh[1024];
  int i = blockIdx.x*1024 + (int)threadIdx.x;
  int v = (i < N_) ? cnt[i] : 0;
  sh[threadIdx.x] = v;
  __syncthreads();
  for (int o = 1; o < 1024; o <<= 1){
    int t = (threadIdx.x >= (unsigned)o) ? sh[threadIdx.x - o] : 0;
    __syncthreads();
    sh[threadIdx.x] += t;
    __syncthreads();
  }
  if (i < N_) rowptr[i] = sh[threadIdx.x] - v;
  if (threadIdx.x == 1023) btot[blockIdx.x] = sh[1023];
}
__global__ void scan2_k(const int* __restrict__ btot, int* __restrict__ boff){
  if (threadIdx.x == 0){
    int s = 0;
    for (int b = 0; b < SCAN_B; b++){ boff[b] = s; s += btot[b]; }
    boff[SCAN_B] = s;
  }
}
__global__ void scan3_k(int* __restrict__ rowptr, const int* __restrict__ boff){
  int i = blockIdx.x*1024 + (int)threadIdx.x;
  if (i < N_) rowptr[i] += boff[blockIdx.x];
  if (i == N_-1) rowptr[N_] = boff[SCAN_B];
}

__global__ void degf_k(const int* __restrict__ cnt, float* __restrict__ degf){
  int n = blockIdx.x*256 + threadIdx.x;
  if (n < N_) degf[n] = fmaxf((float)cnt[n], 1.0f);
}

// also scatters edge_attr into CSR order (so compute_w needs no indirection)
__global__ void scatter_k(const int* __restrict__ src, const int* __restrict__ dst,
                          const float* __restrict__ ea,
                          const int* __restrict__ rowptr, int* __restrict__ fill,
                          int* __restrict__ srcsort, float* __restrict__ easort){
  int e = blockIdx.x*256 + threadIdx.x;
  if (e >= E_) return;
  int d = dst[e];
  int pos = rowptr[d] + atomicAdd(&fill[d], 1);
  srcsort[pos] = src[e];
  ((float2*)easort)[pos] = ((const float2*)ea)[e];
}

// ============================ casts ============================
__global__ void cast_k(const float* __restrict__ in, bf16* __restrict__ out, int n){
  int i = blockIdx.x*256 + threadIdx.x;
  if (i < n) out[i] = __float2bfloat16(in[i]);
}
// in: [batch][R][Cc] fp32 -> out: [batch][Cc][R] bf16 (N x K layout for GEMM B^T)
__global__ void tcast_k(const float* __restrict__ in, bf16* __restrict__ out, int R, int Cc){
  const float* ip = in + (size_t)blockIdx.y*R*Cc;
  bf16* op = out + (size_t)blockIdx.y*R*Cc;
  int i = blockIdx.x*256 + threadIdx.x;
  if (i >= R*Cc) return;
  int c = i / R, r = i - c*R;
  op[i] = __float2bfloat16(ip[(size_t)r*Cc + c]);
}
// g[l]: [C, K*C] -> gGT[l]: [c'][k*C+c] = g[c][k*C+c']   (B^T layout for t-GEMM)
__global__ void gtcast_k(const float* __restrict__ in, bf16* __restrict__ out){
  const float* ip = in + (size_t)blockIdx.y*C_*(K_*C_);
  bf16* op = out + (size_t)blockIdx.y*C_*(K_*C_);
  int i = blockIdx.x*256 + threadIdx.x;   // < 131072
  int co = i >> 10;
  int rem = i & 1023;
  int k = rem >> 7, c = rem & 127;
  op[i] = __float2bfloat16(ip[(size_t)c*(K_*C_) + k*C_ + co]);
}
// LSTM weights: permute gate rows so within each wave's 64 cols, nt==gate, lrow==channel.
// pi(r): gate=r>>8, j=r&255 -> (j>>5)*128 + ((j>>4)&1)*64 + gate*16 + (j&15)
__global__ void permcast_k(const float* __restrict__ in, bf16* __restrict__ out, int Kdim){
  const float* ip = in + (size_t)blockIdx.y*1024*Kdim;
  bf16* op = out + (size_t)blockIdx.y*1024*Kdim;
  int i = blockIdx.x*256 + threadIdx.x;
  if (i >= 1024*Kdim) return;
  int r = i / Kdim, k = i - r*Kdim;
  int gsel = r >> 8, jj = r & 255;
  int p = ((jj >> 5) << 7) + (((jj >> 4) & 1) << 6) + (gsel << 4) + (jj & 15);
  op[(size_t)p*Kdim + k] = __float2bfloat16(ip[i]);
}
__global__ void biassum_k(const float* __restrict__ bih, const float* __restrict__ bhh,
                          float* __restrict__ bs){
  int i = blockIdx.x*256 + threadIdx.x;  // < 2048, original gate-major order
  if (i < 2048) bs[i] = bih[i] + bhh[i];
}

// ============================ bf16 MFMA GEMM (generic, BK=32, xor-swizzled LDS) ============
// Staging slot c holds row=c>>2, chunk j=(c&3)^((c>>3)&3): coalesced 64B-contiguous global
// reads per row, and fragment reads at slot row*4+(lk^((row>>1)&3)) are 2 lanes/bank (free).
// C[M,Nn] = A1[M,K1] @ B1[Nn,K1]^T (+ A2[M,K2] @ B2[Nn,K2]^T) (+bias1) (relu)
template<int OUTBF16>
__global__ __launch_bounds__(256)
void gemm_bf16_k(const bf16* __restrict__ A1, const bf16* __restrict__ B1, int K1,
                 const bf16* __restrict__ A2, const bf16* __restrict__ B2, int K2,
                 const float* __restrict__ bias1,
                 void* __restrict__ Cout, int M, int Nn, int relu)
{
  __shared__ short As[128*32];
  __shared__ short Bs[128*32];
  const int tid  = threadIdx.x;
  const int wave = tid >> 6, lane = tid & 63;
  const int m0 = blockIdx.y*128, n0 = blockIdx.x*128;
  const int wm = (wave >> 1)*64, wn = (wave & 1)*64;
  const int lrow = lane & 15, lk = lane >> 4;
  floatx4 acc[4][4] = {};

  #pragma unroll
  for (int phase = 0; phase < 2; ++phase){
    const bf16* A = phase ? A2 : A1;
    const bf16* B = phase ? B2 : B1;
    const int   K = phase ? K2 : K1;
    if (A == nullptr) continue;
    for (int k0 = 0; k0 < K; k0 += 32){
      #pragma unroll
      for (int i = 0; i < 2; ++i){
        const int c    = i*256 + wave*64 + lane;
        const int row  = c >> 2;
        const int jsrc = (c & 3) ^ ((c >> 3) & 3);
        int ar = m0 + row; if (ar >= M) ar = M - 1;
        gload_lds16(A + (size_t)ar*K + k0 + jsrc*8,         As + (size_t)c*8);
        gload_lds16(B + (size_t)(n0 + row)*K + k0 + jsrc*8, Bs + (size_t)c*8);
      }
      __syncthreads();
      short8 af[4], bfr[4];
      #pragma unroll
      for (int t = 0; t < 4; ++t){
        const int ra = wm + t*16 + lrow;
        const int rb = wn + t*16 + lrow;
        af[t]  = *(const short8*)&As[(ra*4 + (lk ^ ((ra >> 1) & 3)))*8];
        bfr[t] = *(const short8*)&Bs[(rb*4 + (lk ^ ((rb >> 1) & 3)))*8];
      }
      #pragma unroll
      for (int mt = 0; mt < 4; ++mt)
        #pragma unroll
        for (int nt = 0; nt < 4; ++nt)
          acc[mt][nt] = __builtin_amdgcn_mfma_f32_16x16x32_bf16(af[mt], bfr[nt], acc[mt][nt], 0, 0, 0);
      __syncthreads();
    }
  }

  float* outf = (float*)Cout;
  bf16*  outb = (bf16*)Cout;
  #pragma unroll
  for (int nt = 0; nt < 4; ++nt){
    const int col = n0 + wn + nt*16 + lrow;
    float bv = bias1 ? bias1[col] : 0.f;
    #pragma unroll
    for (int mt = 0; mt < 4; ++mt){
      #pragma unroll
      for (int r = 0; r < 4; ++r){
        const int row = m0 + wm + mt*16 + lk*4 + r;   // C/D: col=lane&15, row=(lane>>4)*4+reg
        if (row >= M) continue;
        float v = acc[mt][nt][r] + bv;
        if (relu) v = fmaxf(v, 0.f);
        if (OUTBF16) outb[(size_t)row*Nn + col] = __float2bfloat16(v);
        else         outf[(size_t)row*Nn + col] = v;
      }
    }
  }
}

// ============================ GMM GEMM, balanced split-K x2 ============================
// hpre = t@G_stacked(K=1024) + h@root(K=128) + bias, split into two 576-K halves that
// co-run in one dispatch (470 blocks vs 235): z=0 does t[:,0:576)+bias -> outA;
// z=1 does t[:,576:1024) + h@root -> outB. Deterministic (separate buffers, no atomics).
__global__ __launch_bounds__(256)
void gmm_split_k(const bf16* __restrict__ tbuf, const bf16* __restrict__ gGTl,
                 const bf16* __restrict__ hin, const bf16* __restrict__ rootTl,
                 const float* __restrict__ bias,
                 float* __restrict__ outA, float* __restrict__ outB, int M)
{
  __shared__ short As[128*32];
  __shared__ short Bs[128*32];
  const int z = blockIdx.z;
  const int tid  = threadIdx.x;
  const int wave = tid >> 6, lane = tid & 63;
  const int m0 = blockIdx.x*128;
  const int wm = (wave >> 1)*64, wn = (wave & 1)*64;
  const int lrow = lane & 15, lk = lane >> 4;
  floatx4 acc[4][4] = {};

  const int k1off = z ? 576 : 0;
  const int k1len = z ? 448 : 576;

  #pragma unroll
  for (int phase = 0; phase < 2; ++phase){
    if (phase == 1 && z == 0) break;
    const bf16* A   = phase ? hin    : tbuf;
    const bf16* B   = phase ? rootTl : gGTl;
    const int   ld  = phase ? C_     : (K_*C_);
    const int   kof = phase ? 0      : k1off;
    const int   Kl  = phase ? C_     : k1len;
    for (int k0 = 0; k0 < Kl; k0 += 32){
      #pragma unroll
      for (int i = 0; i < 2; ++i){
        const int c    = i*256 + wave*64 + lane;
        const int row  = c >> 2;
        const int jsrc = (c & 3) ^ ((c >> 3) & 3);
        int ar = m0 + row; if (ar >= M) ar = M - 1;
        gload_lds16(A + (size_t)ar*ld + kof + k0 + jsrc*8, As + (size_t)c*8);
        gload_lds16(B + (size_t)row*ld + kof + k0 + jsrc*8, Bs + (size_t)c*8);
      }
      __syncthreads();
      short8 af[4], bfr[4];
      #pragma unroll
      for (int t = 0; t < 4; ++t){
        const int ra = wm + t*16 + lrow;
        const int rb = wn + t*16 + lrow;
        af[t]  = *(const short8*)&As[(ra*4 + (lk ^ ((ra >> 1) & 3)))*8];
        bfr[t] = *(const short8*)&Bs[(rb*4 + (lk ^ ((rb >> 1) & 3)))*8];
      }
      #pragma unroll
      for (int mt = 0; mt < 4; ++mt)
        #pragma unroll
        for (int nt = 0; nt < 4; ++nt)
          acc[mt][nt] = __builtin_amdgcn_mfma_f32_16x16x32_bf16(af[mt], bfr[nt], acc[mt][nt], 0, 0, 0);
      __syncthreads();
    }
  }

  float* out = z ? outB : outA;
  #pragma unroll
  for (int nt = 0; nt < 4; ++nt){
    const int col = wn + nt*16 + lrow;
    const float bv = z ? 0.f : bias[col];
    #pragma unroll
    for (int mt = 0; mt < 4; ++mt){
      #pragma unroll
      for (int r = 0; r < 4; ++r){
        const int row = m0 + wm + mt*16 + lk*4 + r;
        if (row >= M) continue;
        out[(size_t)row*C_ + col] = acc[mt][nt][r] + bv;
      }
    }
  }
}

// ============================ fused LSTM step, both directions ============================
// 512-thread blocks covering 128 rows x 256 permuted cols (2 m-waves x 4 n-waves, per-wave
// 64x64 unchanged): halves the A-tile (x_t, h) re-reads vs 128-col blocks while keeping the
// r6/r10 n-fastest ordering (8->4 concurrent sharers per A-tile, still multi-XCD MLP).
// xor-swizzled LDS (coalesced + conflict-free). Weights permuted so nt==gate; pointwise
// LSTM in registers. c-state bf16. hpf/hpb==nullptr -> step 0. hof==nullptr -> final step.
__global__ __launch_bounds__(512)
void lstm_step2_k(const bf16* __restrict__ A1f, const bf16* __restrict__ A1b,
                  const bf16* __restrict__ wihp, const bf16* __restrict__ whhp,
                  const bf16* __restrict__ hpf, const bf16* __restrict__ hpb,
                  const float* __restrict__ bsum,   // [2][4][H] combined bias
                  bf16* __restrict__ hof, bf16* __restrict__ hob,
                  bf16* __restrict__ csf, bf16* __restrict__ csb,
                  const float* __restrict__ attw,   // [2][H]
                  float* __restrict__ alf, float* __restrict__ alb,
                  int M)
{
  __shared__ short As[128*32];   // 8 KB
  __shared__ short Bs[256*32];   // 16 KB
  const int dir = blockIdx.z;
  const bf16* A1 = dir ? A1b : A1f;
  const bf16* A2 = dir ? hpb : hpf;
  const bf16* B1 = wihp + (size_t)dir*4*H_*C_;
  const bf16* B2 = whhp + (size_t)dir*4*H_*H_;
  bf16* hout = dir ? hob : hof;
  bf16* cst  = dir ? csb : csf;
  float* alpha = dir ? alb : alf;
  const float* bsd = bsum + (size_t)dir*4*H_;
  const float* awd = attw + (size_t)dir*H_;

  const int tid  = threadIdx.x;
  const int wave = tid >> 6, lane = tid & 63;
  const int m0 = blockIdx.y*128, n0 = blockIdx.x*256;
  const int wm = (wave >> 2)*64, wn = (wave & 3)*64;
  const int lrow = lane & 15, lk = lane >> 4;
  floatx4 acc[4][4] = {};

  #pragma unroll
  for (int phase = 0; phase < 2; ++phase){
    const bf16* A = phase ? A2 : A1;
    const bf16* B = phase ? B2 : B1;
    const int   K = phase ? H_ : C_;
    if (A == nullptr) continue;
    for (int k0 = 0; k0 < K; k0 += 32){
      // 512 A-chunks + 1024 B-chunks = 1536; 3 iters x 8 waves x 64 lanes.
      // Wave ranges are 64-aligned so the A/B split at 512 is wave-uniform.
      #pragma unroll
      for (int i = 0; i < 3; ++i){
        const int t = i*512 + wave*64 + lane;
        if (t < 512){
          const int c = t, row = c >> 2, jsrc = (c & 3) ^ ((c >> 3) & 3);
          int ar = m0 + row; if (ar >= M) ar = M - 1;
          gload_lds16(A + (size_t)ar*K + k0 + jsrc*8, As + (size_t)c*8);
        } else {
          const int c = t - 512, row = c >> 2, jsrc = (c & 3) ^ ((c >> 3) & 3);
          gload_lds16(B + (size_t)(n0 + row)*K + k0 + jsrc*8, Bs + (size_t)c*8);
        }
      }
      __syncthreads();
      short8 af[4], bfr[4];
      #pragma unroll
      for (int t = 0; t < 4; ++t){
        const int ra = wm + t*16 + lrow;
        const int rb = wn + t*16 + lrow;
        af[t]  = *(const short8*)&As[(ra*4 + (lk ^ ((ra >> 1) & 3)))*8];
        bfr[t] = *(const short8*)&Bs[(rb*4 + (lk ^ ((rb >> 1) & 3)))*8];
      }
      #pragma unroll
      for (int mt = 0; mt < 4; ++mt)
        #pragma unroll
        for (int nt = 0; nt < 4; ++nt)
          acc[mt][nt] = __builtin_amdgcn_mfma_f32_16x16x32_bf16(af[mt], bfr[nt], acc[mt][nt], 0, 0, 0);
      __syncthreads();
    }
  }

  // ---- register-resident pointwise: lane owns channel j, 16 rows; acc[mt][gate][r] ----
  const int q = (n0 + wn) >> 6;                          // 0..15 across permuted cols
  const int j = (q >> 1)*32 + (q & 1)*16 + lrow;         // global channel in [0,H)
  const float bi = bsd[0*H_ + j], bff = bsd[1*H_ + j];
  const float bg = bsd[2*H_ + j], bo  = bsd[3*H_ + j];
  const float aw = awd[j];
  #pragma unroll
  for (int mt = 0; mt < 4; ++mt){
    #pragma unroll
    for (int r = 0; r < 4; ++r){
      const int row = m0 + wm + mt*16 + lk*4 + r;
      const bool ok = row < M;
      const size_t idx = (size_t)row*H_ + j;
      float co = 0.f;
      if (A2 && ok) co = __bfloat162float(cst[idx]);
      float ig = sigm_f(acc[mt][0][r] + bi);
      float fg = sigm_f(acc[mt][1][r] + bff);
      float gt = tanh_f(acc[mt][2][r] + bg);
      float og = sigm_f(acc[mt][3][r] + bo);
      float cv = fg*co + ig*gt;
      float hv = og*tanh_f(cv);
      if (ok && hout){                  // final step: h/c never read again -> skip stores
        cst[idx]  = __float2bfloat16(cv);
        hout[idx] = __float2bfloat16(hv);
      }
      float att = ok ? hv*aw : 0.f;
      att += __shfl_xor(att, 1);
      att += __shfl_xor(att, 2);
      att += __shfl_xor(att, 4);
      att += __shfl_xor(att, 8);
      if (lrow == 0 && ok) atomicAdd(&alpha[row], att);
    }
  }
}

// ============================ GMM layer pieces ============================
// edge weights in CSR order (easort is pre-sorted), bf16 output (16 B/edge)
__global__ void compute_w_k(const float* __restrict__ easort, const float* __restrict__ mu,
                            const float* __restrict__ sigma, bf16* __restrict__ wsrt)
{
  int e = blockIdx.x*256 + threadIdx.x;
  if (e >= E_) return;
  float2 a = ((const float2*)easort)[e];
  short8 o;
  #pragma unroll
  for (int k = 0; k < 8; k++){
    float d0 = a.x - mu[2*k],  d1 = a.y - mu[2*k+1];
    float s0 = sigma[2*k],     s1 = sigma[2*k+1];
    float t = -0.5f*(d0*d0/(1e-15f + s0*s0) + d1*d1/(1e-15f + s1*s1));
    o[k] = __builtin_bit_cast(short, __float2bfloat16(expf(t)));
  }
  *(short8*)(wsrt + (size_t)e*8) = o;
}

// t[d,k,:] = (1/deg_d) * sum_{e->d} w[e,k] * h[src_e,:]  -- wave per dst node.
__global__ __launch_bounds__(256)
void aggregate_t_k(const bf16* __restrict__ h, const bf16* __restrict__ wsrt,
                   const int* __restrict__ rowptr, const int* __restrict__ srcsort,
                   const float* __restrict__ degf, bf16* __restrict__ t)
{
  int node = blockIdx.x*4 + (threadIdx.x >> 6);
  int lane = threadIdx.x & 63;
  if (node >= N_) return;
  int p0 = rowptr[node], p1 = rowptr[node+1];
  float ax[8] = {}, ay[8] = {};
  for (int p = p0; p < p1; p++){
    int s = srcsort[p];
    short8 wv = *(const short8*)(wsrt + (size_t)p*8);
    float2 v = __bfloat1622float2(((const __hip_bfloat162*)(h + (size_t)s*C_))[lane]);
    #pragma unroll
    for (int k = 0; k < 8; k++){
      float wk = bf2f(wv[k]);
      ax[k] = fmaf(wk, v.x, ax[k]);
      ay[k] = fmaf(wk, v.y, ay[k]);
    }
  }
  float inv = 1.0f / degf[node];
  __hip_bfloat162* tp = (__hip_bfloat162*)(t + (size_t)node*(K_*C_));
  #pragma unroll
  for (int k = 0; k < 8; k++){
    __hip_bfloat162 o; o.x = __float2bfloat16(ax[k]*inv); o.y = __float2bfloat16(ay[k]*inv);
    tp[k*64 + lane] = o;
  }
}

// per-channel sum/sumsq of (hA+hB) into stats
__global__ __launch_bounds__(256)
void gmm_stats2_k(const float* __restrict__ hA, const float* __restrict__ hB,
                  float* __restrict__ stats)
{
  int c = threadIdx.x & 127;
  int sub = threadIdx.x >> 7;
  float s = 0.f, s2 = 0.f;
  for (int r = blockIdx.x*2 + sub; r < N_; r += gridDim.x*2){
    size_t i = (size_t)r*C_ + c;
    float v = hA[i] + hB[i];
    s += v; s2 += v*v;
  }
  atomicAdd(&stats[c], s);
  atomicAdd(&stats[c+128], s2);
}

__global__ void bn_apply2_k(const float* __restrict__ hA, const float* __restrict__ hB,
                            const float* __restrict__ stats,
                            const float* __restrict__ gamma, const float* __restrict__ beta,
                            bf16* __restrict__ outp, int relu)
{
  int i = blockIdx.x*256 + threadIdx.x;
  if (i >= N_*C_) return;
  int c = i & 127;
  float mean = stats[c] * (1.0f/N_);
  float var  = stats[c+128] * (1.0f/N_) - mean*mean;
  float rstd = rsqrtf(var + 1e-5f);
  float v = ((hA[i] + hB[i]) - mean)*rstd*gamma[c] + beta[c];
  if (relu) v = fmaxf(v, 0.f);
  outp[i] = __float2bfloat16(v);
}

// ============================ JK softmax + pooling ============================
__global__ void jk_pool_k(const float* __restrict__ x, const bf16* __restrict__ hlist,
                          const float* __restrict__ alpha, const int* __restrict__ batch,
                          float* __restrict__ hgraph, float* __restrict__ gcnt)
{
  int n = blockIdx.x, c = threadIdx.x;
  float a[5]; float mx = -1e30f;
  #pragma unroll
  for (int t = 0; t < 5; t++){ a[t] = alpha[(size_t)t*N_ + n]; mx = fmaxf(mx, a[t]); }
  float ssum = 0.f;
  #pragma unroll
  for (int t = 0; t < 5; t++){ a[t] = expf(a[t] - mx); ssum += a[t]; }
  float inv = 1.0f/ssum;
  float val = a[0]*inv*x[(size_t)n*C_ + c];
  #pragma unroll
  for (int t = 1; t < 5; t++)
    val = fmaf(a[t]*inv, __bfloat162float(hlist[((size_t)(t-1)*N_ + n)*C_ + c]), val);
  int bg = batch[n];
  atomicAdd(&hgraph[(size_t)bg*C_ + c], val);
  if (c == 0) atomicAdd(&gcnt[bg], 1.0f);
}

__global__ void pool_div_k(const float* __restrict__ hg, const float* __restrict__ gcnt,
                           bf16* __restrict__ hgb){
  int i = blockIdx.x*256 + threadIdx.x;
  if (i < B_*C_) hgb[i] = __float2bfloat16(hg[i] / fmaxf(gcnt[i >> 7], 1.0f));
}

// ============================ final LayerNorm ============================
__global__ __launch_bounds__(256)
void layernorm_k(float* __restrict__ z, const float* __restrict__ g, const float* __restrict__ b){
  int row = blockIdx.x, j = threadIdx.x;
  float v = z[(size_t)row*NOUT_ + j];
  float s = v, s2 = v*v;
  #pragma unroll
  for (int o = 32; o; o >>= 1){ s += __shfl_down(s, o); s2 += __shfl_down(s2, o); }
  __shared__ float sh[8];
  int w = j >> 6;
  if ((j & 63) == 0){ sh[w] = s; sh[4+w] = s2; }
  __syncthreads();
  float st  = sh[0] + sh[1] + sh[2] + sh[3];
  float st2 = sh[4] + sh[5] + sh[6] + sh[7];
  float mean = st * (1.0f/NOUT_);
  float var  = st2 * (1.0f/NOUT_) - mean*mean;
  float rstd = rsqrtf(var + 1e-5f);
  z[(size_t)row*NOUT_ + j] = (v - mean)*rstd*g[j] + b[j];
}

// ============================ launch ============================
extern "C" void kernel_launch(void* const* d_in, const int* in_sizes, int n_in,
                              void* d_out, int out_size, void* d_ws, size_t ws_size,
                              hipStream_t stream)
{
  (void)in_sizes; (void)n_in; (void)out_size; (void)ws_size;
  const float* x     = (const float*)d_in[0];
  const int*   eidx  = (const int*)  d_in[1];
  const float* eattr = (const float*)d_in[2];
  const int*   batch = (const int*)  d_in[3];
  const float* g     = (const float*)d_in[4];
  const float* root  = (const float*)d_in[5];
  const float* bias  = (const float*)d_in[6];
  const float* mu    = (const float*)d_in[7];
  const float* sigma = (const float*)d_in[8];
  const float* bng   = (const float*)d_in[9];
  const float* bnb   = (const float*)d_in[10];
  const float* w_ih  = (const float*)d_in[11];
  const float* w_hh  = (const float*)d_in[12];
  const float* b_ih  = (const float*)d_in[13];
  const float* b_hh  = (const float*)d_in[14];
  const float* attw  = (const float*)d_in[15];
  // d_in[16] = att_b: softmax-shift-invariant, unused
  const float* p1w   = (const float*)d_in[17];
  const float* p1b   = (const float*)d_in[18];
  const float* p2w   = (const float*)d_in[19];
  const float* p2b   = (const float*)d_in[20];
  const float* lng   = (const float*)d_in[21];
  const float* lnb   = (const float*)d_in[22];
  float* outp = (float*)d_out;

  const int* src = eidx;
  const int* dst = eidx + E_;

  // ---- workspace carve (~205 MB) ----
  size_t off = 0;
  char* wsb = (char*)d_ws;
  auto carve = [&](size_t bytes)->void*{ void* p = wsb + off; off = align256(off + bytes); return p; };
  bf16*  hlist  = (bf16*) carve((size_t)L_*N_*C_*2);        // 30.7 MB  h_list[1..4] bf16
  void*  big    =         carve((size_t)N_*(K_*C_)*2);      // 61.4 MB: t bf16
  void*  uni    =         carve((size_t)6*N_*H_*2 + 256);   // GMM: wsrt+hpreA+hpreB | LSTM: 2x(hA,hB,c)
  bf16*  xb     = (bf16*) carve((size_t)N_*C_*2);           // x in bf16
  float* alpha  = (float*)carve((size_t)(L_+1)*N_*4);
  float* hgraph = (float*)carve((size_t)B_*C_*4);
  bf16*  hgb    = (bf16*) carve((size_t)B_*C_*2);
  float* gcnt   = (float*)carve((size_t)B_*4);
  bf16*  z1b    = (bf16*) carve((size_t)B_*NHID_*2);
  float* bnstats= (float*)carve((size_t)L_*2*C_*4);
  float* degf   = (float*)carve((size_t)N_*4);
  int* cnt      = (int*)  carve((size_t)N_*4);
  int* rowptr   = (int*)  carve((size_t)(N_+1)*4);
  int* fill     = (int*)  carve((size_t)N_*4);
  int* srcsort  = (int*)  carve((size_t)E_*4);
  float* easort = (float*)carve((size_t)E_*2*4);
  int* btot     = (int*)  carve((size_t)(SCAN_B+1)*4);
  int* boff     = (int*)  carve((size_t)(SCAN_B+1)*4);
  // bf16 weights
  bf16* gGT   = (bf16*)carve((size_t)L_*C_*(K_*C_)*2);      // [L][c'][k*C+c] for t-GEMM
  bf16* rootT = (bf16*)carve((size_t)L_*C_*C_*2);           // [L][C, C]
  bf16* wihp  = (bf16*)carve((size_t)2*4*H_*C_*2);          // [2][1024][128] gate-permuted
  bf16* whhp  = (bf16*)carve((size_t)2*4*H_*H_*2);          // [2][1024][256] gate-permuted
  float* bsum = (float*)carve((size_t)2*4*H_*4);            // b_ih+b_hh, original order
  bf16* p1T   = (bf16*)carve((size_t)NHID_*C_*2);
  bf16* p2T   = (bf16*)carve((size_t)NOUT_*NHID_*2);

  // union aliases (GMM phase vs LSTM phase)
  bf16*  wsrt   = (bf16*)uni;                                // [E,8] bf16  7.7 MB
  float* hpreA  = (float*)((char*)uni + (size_t)E_*K_*2);    // [N,C] fp32 15.4 MB
  float* hpreB  = hpreA + (size_t)N_*C_;                     // [N,C] fp32 15.4 MB
  bf16*  hAf    = (bf16*)uni;                                // per-dir h ping/pong + c, each [N,H] bf16
  bf16*  hAb    = hAf + (size_t)N_*H_;
  bf16*  hBf    = hAb + (size_t)N_*H_;
  bf16*  hBb    = hBf + (size_t)N_*H_;
  bf16*  csf    = hBb + (size_t)N_*H_;
  bf16*  csb    = csf + (size_t)N_*H_;
  bf16*  tbuf   = (bf16*)big;                                // [N,K*C] bf16

  // ---- zero-init (ws is poisoned every call) ----
  hipMemsetAsync(cnt,     0, (size_t)N_*4, stream);
  hipMemsetAsync(fill,    0, (size_t)N_*4, stream);
  hipMemsetAsync(bnstats, 0, (size_t)L_*2*C_*4, stream);
  hipMemsetAsync(hgraph,  0, (size_t)B_*C_*4, stream);
  hipMemsetAsync(gcnt,    0, (size_t)B_*4, stream);
  hipMemsetAsync(alpha,   0, (size_t)(L_+1)*N_*4, stream);

  const dim3 blk(256);

  // ---- CSR build ----
  hist_k  <<<(E_+255)/256, 256, 0, stream>>>(dst, cnt);
  scan1_k <<<SCAN_B, 1024, 0, stream>>>(cnt, rowptr, btot);
  scan2_k <<<1, 64, 0, stream>>>(btot, boff);
  scan3_k <<<SCAN_B, 1024, 0, stream>>>(rowptr, boff);
  degf_k  <<<(N_+255)/256, 256, 0, stream>>>(cnt, degf);
  scatter_k<<<(E_+255)/256, 256, 0, stream>>>(src, dst, eattr, rowptr, fill, srcsort, easort);

  // ---- weight/activation casts ----
  cast_k <<<(N_*C_+255)/256, blk, 0, stream>>>(x, xb, N_*C_);
  gtcast_k<<<dim3((C_*K_*C_)/256, L_), blk, 0, stream>>>(g, gGT);
  tcast_k<<<dim3((C_*C_+255)/256,   L_), blk, 0, stream>>>(root, rootT, C_,   C_);
  permcast_k<<<dim3((1024*C_+255)/256, 2), blk, 0, stream>>>(w_ih, wihp, C_);
  permcast_k<<<dim3((1024*H_+255)/256, 2), blk, 0, stream>>>(w_hh, whhp, H_);
  biassum_k<<<8, blk, 0, stream>>>(b_ih, b_hh, bsum);
  tcast_k<<<dim3((C_*NHID_+255)/256, 1), blk, 0, stream>>>(p1w, p1T, C_,    NHID_);
  tcast_k<<<dim3((NHID_*NOUT_+255)/256,1), blk, 0, stream>>>(p2w, p2T, NHID_, NOUT_);

  const int MB = (N_ + 127)/128;  // 235

  // ---- 4 GMMConv + BN layers (t-formulation, split-K GEMM) ----
  for (int l = 0; l < L_; l++){
    const bf16* hin = l ? (hlist + (size_t)(l-1)*N_*C_) : xb;
    compute_w_k<<<(E_+255)/256, blk, 0, stream>>>(easort, mu + (size_t)l*K_*2, sigma + (size_t)l*K_*2, wsrt);
    aggregate_t_k<<<N_/4, blk, 0, stream>>>(hin, wsrt, rowptr, srcsort, degf, tbuf);
    gmm_split_k<<<dim3(MB, 1, 2), blk, 0, stream>>>(
        tbuf, gGT + (size_t)l*C_*K_*C_, hin, rootT + (size_t)l*C_*C_,
        bias + (size_t)l*C_, hpreA, hpreB, N_);
    gmm_stats2_k<<<120, blk, 0, stream>>>(hpreA, hpreB, bnstats + l*2*C_);
    bn_apply2_k<<<(N_*C_+255)/256, blk, 0, stream>>>(hpreA, hpreB, bnstats + l*2*C_,
        bng + (size_t)l*C_, bnb + (size_t)l*C_, hlist + (size_t)l*N_*C_, (l < L_-1) ? 1 : 0);
  }

  // ---- bidirectional JK-LSTM over xs = [x, h1..h4] (T=5), both dirs per dispatch ----
  {
    const bf16 *hpf = nullptr, *hpb = nullptr;
    for (int s = 0; s < 5; s++){
      int tf = s, tb = 4 - s;
      const bf16* xtf = tf ? (hlist + (size_t)(tf-1)*N_*C_) : xb;
      const bf16* xtb = tb ? (hlist + (size_t)(tb-1)*N_*C_) : xb;
      bf16* hof = (s == 4) ? nullptr : ((s & 1) ? hBf : hAf);
      bf16* hob = (s == 4) ? nullptr : ((s & 1) ? hBb : hAb);
      lstm_step2_k<<<dim3(4, MB, 2), 512, 0, stream>>>(
          xtf, xtb, wihp, whhp, hpf, hpb, bsum, hof, hob, csf, csb,
          attw, alpha + (size_t)tf*N_, alpha + (size_t)tb*N_, N_);
      hpf = hof; hpb = hob;
    }
  }

  // ---- JK attention softmax + weighted sum + global mean pool ----
  jk_pool_k<<<N_, 128, 0, stream>>>(x, hlist, alpha, batch, hgraph, gcnt);
  pool_div_k<<<(B_*C_+255)/256, blk, 0, stream>>>(hgraph, gcnt, hgb);

  // ---- MLP head + LayerNorm ----
  gemm_bf16_k<1><<<dim3(NHID_/128, B_/128), blk, 0, stream>>>(
      hgb, p1T, C_, nullptr, nullptr, 0, p1b, z1b, B_, NHID_, 1);
  gemm_bf16_k<0><<<dim3(NOUT_/128, B_/128), blk, 0, stream>>>(
      z1b, p2T, NHID_, nullptr, nullptr, 0, p2b, outp, B_, NOUT_, 0);
  layernorm_k<<<B_, 256, 0, stream>>>(outp, lng, lnb);
}

// Round 12
// 1213.000 us; speedup vs baseline: 1.2687x; 1.2687x over previous
//
#include <hip/hip_runtime.h>
#include <hip/hip_bf16.h>
#include <math.h>

#define N_    30000
#define E_    480000
#define C_    128
#define K_    8
#define L_    4
#define H_    256
#define NHID_ 512
#define NOUT_ 256
#define B_    1024
#define SCAN_B 30   // ceil(N_/1024)

typedef __attribute__((ext_vector_type(8))) short short8;
typedef __attribute__((ext_vector_type(4))) float floatx4;
typedef __hip_bfloat16 bf16;

static inline size_t align256(size_t x){ return (x + 255) & ~(size_t)255; }

__device__ __forceinline__ void gload_lds16(const void* g, void* l){
  __builtin_amdgcn_global_load_lds((const __attribute__((address_space(1))) void*)g,
                                   (__attribute__((address_space(3))) void*)l, 16, 0, 0);
}
__device__ __forceinline__ float bf2f(short s){
  union { unsigned u; float f; } x; x.u = ((unsigned)(unsigned short)s) << 16; return x.f;
}
// fast sigmoid/tanh: v_exp-based, ~1e-5 rel err (negligible vs bf16 rounding)
__device__ __forceinline__ float sigm_f(float x){ return __builtin_amdgcn_rcpf(1.f + __expf(-x)); }
__device__ __forceinline__ float tanh_f(float x){ return 1.f - 2.f*__builtin_amdgcn_rcpf(1.f + __expf(2.f*x)); }

// ============================ CSR build ============================
__global__ void hist_k(const int* __restrict__ dst, int* __restrict__ cnt){
  int e = blockIdx.x*256 + threadIdx.x;
  if (e < E_) atomicAdd(&cnt[dst[e]], 1);
}

__global__ void scan1_k(const int* __restrict__ cnt, int* __restrict__ rowptr, int* __restrict__ btot){
  __shared__ int sh[1024];
  int i = blockIdx.x*1024 + (int)threadIdx.x;
  int v = (i < N_) ? cnt[i] : 0;
  sh[threadIdx.x] = v;
  __syncthreads();
  for (int o = 1; o < 1024; o <<= 1){
    int t = (threadIdx.x >= (unsigned)o) ? sh[threadIdx.x - o] : 0;
    __syncthreads();
    sh[threadIdx.x] += t;
    __syncthreads();
  }
  if (i < N_) rowptr[i] = sh[threadIdx.x] - v;
  if (threadIdx.x == 1023) btot[blockIdx.x] = sh[1023];
}
__global__ void scan2_k(const int* __restrict__ btot, int* __restrict__ boff){
  if (threadIdx.x == 0){
    int s = 0;
    for (int b = 0; b < SCAN_B; b++){ boff[b] = s; s += btot[b]; }
    boff[SCAN_B] = s;
  }
}
__global__ void scan3_k(int* __restrict__ rowptr, const int* __restrict__ boff){
  int i = blockIdx.x*1024 + (int)threadIdx.x;
  if (i < N_) rowptr[i] += boff[blockIdx.x];
  if (i == N_-1) rowptr[N_] = boff[SCAN_B];
}

__global__ void degf_k(const int* __restrict__ cnt, float* __restrict__ degf){
  int n = blockIdx.x*256 + threadIdx.x;
  if (n < N_) degf[n] = fmaxf((float)cnt[n], 1.0f);
}

// also scatters edge_attr into CSR order (so compute_w needs no indirection)
__global__ void scatter_k(const int* __restrict__ src, const int* __restrict__ dst,
                          const float* __restrict__ ea,
                          const int* __restrict__ rowptr, int* __restrict__ fill,
                          int* __restrict__ srcsort, float* __restrict__ easort){
  int e = blockIdx.x*256 + threadIdx.x;
  if (e >= E_) return;
  int d = dst[e];
  int pos = rowptr[d] + atomicAdd(&fill[d], 1);
  srcsort[pos] = src[e];
  ((float2*)easort)[pos] = ((const float2*)ea)[e];
}

// ============================ casts ============================
__global__ void cast_k(const float* __restrict__ in, bf16* __restrict__ out, int n){
  int i = blockIdx.x*256 + threadIdx.x;
  if (i < n) out[i] = __float2bfloat16(in[i]);
}
// in: [batch][R][Cc] fp32 -> out: [batch][Cc][R] bf16 (N x K layout for GEMM B^T)
__global__ void tcast_k(const float* __restrict__ in, bf16* __restrict__ out, int R, int Cc){
  const float* ip = in + (size_t)blockIdx.y*R*Cc;
  bf16* op = out + (size_t)blockIdx.y*R*Cc;
  int i = blockIdx.x*256 + threadIdx.x;
  if (i >= R*Cc) return;
  int c = i / R, r = i - c*R;
  op[i] = __float2bfloat16(ip[(size_t)r*Cc + c]);
}
// g[l]: [C, K*C] -> gGT[l]: [c'][k*C+c] = g[c][k*C+c']   (B^T layout for t-GEMM)
__global__ void gtcast_k(const float* __restrict__ in, bf16* __restrict__ out){
  const float* ip = in + (size_t)blockIdx.y*C_*(K_*C_);
  bf16* op = out + (size_t)blockIdx.y*C_*(K_*C_);
  int i = blockIdx.x*256 + threadIdx.x;   // < 131072
  int co = i >> 10;
  int rem = i & 1023;
  int k = rem >> 7, c = rem & 127;
  op[i] = __float2bfloat16(ip[(size_t)c*(K_*C_) + k*C_ + co]);
}
// LSTM weights: permute gate rows so within each wave's 64 cols, nt==gate, lrow==channel.
// pi(r): gate=r>>8, j=r&255 -> (j>>5)*128 + ((j>>4)&1)*64 + gate*16 + (j&15)
__global__ void permcast_k(const float* __restrict__ in, bf16* __restrict__ out, int Kdim){
  const float* ip = in + (size_t)blockIdx.y*1024*Kdim;
  bf16* op = out + (size_t)blockIdx.y*1024*Kdim;
  int i = blockIdx.x*256 + threadIdx.x;
  if (i >= 1024*Kdim) return;
  int r = i / Kdim, k = i - r*Kdim;
  int gsel = r >> 8, jj = r & 255;
  int p = ((jj >> 5) << 7) + (((jj >> 4) & 1) << 6) + (gsel << 4) + (jj & 15);
  op[(size_t)p*Kdim + k] = __float2bfloat16(ip[i]);
}
__global__ void biassum_k(const float* __restrict__ bih, const float* __restrict__ bhh,
                          float* __restrict__ bs){
  int i = blockIdx.x*256 + threadIdx.x;  // < 2048, original gate-major order
  if (i < 2048) bs[i] = bih[i] + bhh[i];
}

// ============================ bf16 MFMA GEMM (generic, BK=32, xor-swizzled LDS) ============
// Staging slot c holds row=c>>2, chunk j=(c&3)^((c>>3)&3): coalesced 64B-contiguous global
// reads per row, and fragment reads at slot row*4+(lk^((row>>1)&3)) are 2 lanes/bank (free).
// C[M,Nn] = A1[M,K1] @ B1[Nn,K1]^T (+ A2[M,K2] @ B2[Nn,K2]^T) (+bias1) (relu)
template<int OUTBF16>
__global__ __launch_bounds__(256)
void gemm_bf16_k(const bf16* __restrict__ A1, const bf16* __restrict__ B1, int K1,
                 const bf16* __restrict__ A2, const bf16* __restrict__ B2, int K2,
                 const float* __restrict__ bias1,
                 void* __restrict__ Cout, int M, int Nn, int relu)
{
  __shared__ short As[128*32];
  __shared__ short Bs[128*32];
  const int tid  = threadIdx.x;
  const int wave = tid >> 6, lane = tid & 63;
  const int m0 = blockIdx.y*128, n0 = blockIdx.x*128;
  const int wm = (wave >> 1)*64, wn = (wave & 1)*64;
  const int lrow = lane & 15, lk = lane >> 4;
  floatx4 acc[4][4] = {};

  #pragma unroll
  for (int phase = 0; phase < 2; ++phase){
    const bf16* A = phase ? A2 : A1;
    const bf16* B = phase ? B2 : B1;
    const int   K = phase ? K2 : K1;
    if (A == nullptr) continue;
    for (int k0 = 0; k0 < K; k0 += 32){
      #pragma unroll
      for (int i = 0; i < 2; ++i){
        const int c    = i*256 + wave*64 + lane;
        const int row  = c >> 2;
        const int jsrc = (c & 3) ^ ((c >> 3) & 3);
        int ar = m0 + row; if (ar >= M) ar = M - 1;
        gload_lds16(A + (size_t)ar*K + k0 + jsrc*8,         As + (size_t)c*8);
        gload_lds16(B + (size_t)(n0 + row)*K + k0 + jsrc*8, Bs + (size_t)c*8);
      }
      __syncthreads();
      short8 af[4], bfr[4];
      #pragma unroll
      for (int t = 0; t < 4; ++t){
        const int ra = wm + t*16 + lrow;
        const int rb = wn + t*16 + lrow;
        af[t]  = *(const short8*)&As[(ra*4 + (lk ^ ((ra >> 1) & 3)))*8];
        bfr[t] = *(const short8*)&Bs[(rb*4 + (lk ^ ((rb >> 1) & 3)))*8];
      }
      #pragma unroll
      for (int mt = 0; mt < 4; ++mt)
        #pragma unroll
        for (int nt = 0; nt < 4; ++nt)
          acc[mt][nt] = __builtin_amdgcn_mfma_f32_16x16x32_bf16(af[mt], bfr[nt], acc[mt][nt], 0, 0, 0);
      __syncthreads();
    }
  }

  float* outf = (float*)Cout;
  bf16*  outb = (bf16*)Cout;
  #pragma unroll
  for (int nt = 0; nt < 4; ++nt){
    const int col = n0 + wn + nt*16 + lrow;
    float bv = bias1 ? bias1[col] : 0.f;
    #pragma unroll
    for (int mt = 0; mt < 4; ++mt){
      #pragma unroll
      for (int r = 0; r < 4; ++r){
        const int row = m0 + wm + mt*16 + lk*4 + r;   // C/D: col=lane&15, row=(lane>>4)*4+reg
        if (row >= M) continue;
        float v = acc[mt][nt][r] + bv;
        if (relu) v = fmaxf(v, 0.f);
        if (OUTBF16) outb[(size_t)row*Nn + col] = __float2bfloat16(v);
        else         outf[(size_t)row*Nn + col] = v;
      }
    }
  }
}

// ============================ GMM GEMM, BK=64, stats fused ============================
// hpre = t@G_stacked(K=1024) + h@root(K=128) + bias; grid = 235 blocks (<1/CU) so every
// barrier drain is fully latency-exposed -> BK=64 halves drains 36->18 at zero occupancy
// cost (r9 showed BK=64 hurts the LSTM by cutting co-resident blocks; here there are none).
// BK=64 xor swizzle: slot c holds row=c>>3, chunk (c&7)^(row&7) -> each row sources one
// contiguous 128B (coalesced); fragment reads land 2 lanes/bank. Same MFMA k-order as BK=32
// -> bit-identical results. Per-column sum/sumsq accumulated into stats[col], stats[128+col].
__global__ __launch_bounds__(256)
void gmm_gemm64_k(const bf16* __restrict__ tbuf, const bf16* __restrict__ gGTl,
                  const bf16* __restrict__ hin, const bf16* __restrict__ rootTl,
                  const float* __restrict__ bias, float* __restrict__ outp,
                  float* __restrict__ stats, int M)
{
  __shared__ short As[128*64];
  __shared__ short Bs[128*64];
  __shared__ float colstat[256];
  const int tid  = threadIdx.x;
  const int wave = tid >> 6, lane = tid & 63;
  const int m0 = blockIdx.x*128;
  const int wm = (wave >> 1)*64, wn = (wave & 1)*64;
  const int lrow = lane & 15, lk = lane >> 4;
  floatx4 acc[4][4] = {};
  colstat[tid] = 0.f;

  #pragma unroll
  for (int phase = 0; phase < 2; ++phase){
    const bf16* A  = phase ? hin    : tbuf;
    const bf16* B  = phase ? rootTl : gGTl;
    const int   ld = phase ? C_     : (K_*C_);
    const int   K  = phase ? C_     : (K_*C_);
    for (int k0 = 0; k0 < K; k0 += 64){
      #pragma unroll
      for (int i = 0; i < 4; ++i){
        const int c    = i*256 + wave*64 + lane;   // slot 0..1023
        const int row  = c >> 3;
        const int jsrc = (c & 7) ^ (row & 7);
        int ar = m0 + row; if (ar >= M) ar = M - 1;
        gload_lds16(A + (size_t)ar*ld + k0 + jsrc*8,  As + (size_t)c*8);
        gload_lds16(B + (size_t)row*ld + k0 + jsrc*8, Bs + (size_t)c*8);
      }
      __syncthreads();
      #pragma unroll
      for (int kk = 0; kk < 2; ++kk){
        short8 af[4], bfr[4];
        #pragma unroll
        for (int t = 0; t < 4; ++t){
          const int ra = wm + t*16 + lrow;
          const int rb = wn + t*16 + lrow;
          af[t]  = *(const short8*)&As[(ra*8 + ((kk*4 + lk) ^ (ra & 7)))*8];
          bfr[t] = *(const short8*)&Bs[(rb*8 + ((kk*4 + lk) ^ (rb & 7)))*8];
        }
        #pragma unroll
        for (int mt = 0; mt < 4; ++mt)
          #pragma unroll
          for (int nt = 0; nt < 4; ++nt)
            acc[mt][nt] = __builtin_amdgcn_mfma_f32_16x16x32_bf16(af[mt], bfr[nt], acc[mt][nt], 0, 0, 0);
      }
      __syncthreads();
    }
  }

  #pragma unroll
  for (int nt = 0; nt < 4; ++nt){
    const int col = wn + nt*16 + lrow;
    const float bv = bias[col];
    float s = 0.f, s2 = 0.f;
    #pragma unroll
    for (int mt = 0; mt < 4; ++mt){
      #pragma unroll
      for (int r = 0; r < 4; ++r){
        const int row = m0 + wm + mt*16 + lk*4 + r;
        if (row >= M) continue;
        float v = acc[mt][nt][r] + bv;
        outp[(size_t)row*C_ + col] = v;
        s += v; s2 += v*v;
      }
    }
    s  += __shfl_down(s, 16);  s  += __shfl_down(s, 32);
    s2 += __shfl_down(s2, 16); s2 += __shfl_down(s2, 32);
    if (lane < 16){
      atomicAdd(&colstat[wn + nt*16 + lane], s);
      atomicAdd(&colstat[128 + wn + nt*16 + lane], s2);
    }
  }
  __syncthreads();
  if (tid < 128){
    atomicAdd(&stats[tid],       colstat[tid]);
    atomicAdd(&stats[128 + tid], colstat[128 + tid]);
  }
}

// ============================ fused LSTM step, both directions ============================
// r6/r10 grid (8 n-tiles fastest, 235 m-tiles, 2 dirs): the 8 A-tile sharers are temporally
// concurrent on 8 XCDs = 8 independent HBM miss streams (max MLP — r7/r8/r11 variants that
// reduced concurrent fetchers all lost). BK=32 xor-swizzled LDS: coalesced, zero conflicts.
// Weights permuted so nt==gate, lrow==channel: pointwise LSTM in registers. c-state bf16.
// hpf/hpb==nullptr -> step 0 (h=c=0). hof==nullptr -> final step (h/c outputs never read).
__global__ __launch_bounds__(256)
void lstm_step2_k(const bf16* __restrict__ A1f, const bf16* __restrict__ A1b,
                  const bf16* __restrict__ wihp, const bf16* __restrict__ whhp,
                  const bf16* __restrict__ hpf, const bf16* __restrict__ hpb,
                  const float* __restrict__ bsum,   // [2][4][H] combined bias
                  bf16* __restrict__ hof, bf16* __restrict__ hob,
                  bf16* __restrict__ csf, bf16* __restrict__ csb,
                  const float* __restrict__ attw,   // [2][H]
                  float* __restrict__ alf, float* __restrict__ alb,
                  int M)
{
  __shared__ short As[128*32];
  __shared__ short Bs[128*32];
  const int dir = blockIdx.z;
  const bf16* A1 = dir ? A1b : A1f;
  const bf16* A2 = dir ? hpb : hpf;
  const bf16* B1 = wihp + (size_t)dir*4*H_*C_;
  const bf16* B2 = whhp + (size_t)dir*4*H_*H_;
  bf16* hout = dir ? hob : hof;
  bf16* cst  = dir ? csb : csf;
  float* alpha = dir ? alb : alf;
  const float* bsd = bsum + (size_t)dir*4*H_;
  const float* awd = attw + (size_t)dir*H_;

  const int tid  = threadIdx.x;
  const int wave = tid >> 6, lane = tid & 63;
  const int m0 = blockIdx.y*128, n0 = blockIdx.x*128;
  const int wm = (wave >> 1)*64, wn = (wave & 1)*64;
  const int lrow = lane & 15, lk = lane >> 4;
  floatx4 acc[4][4] = {};

  #pragma unroll
  for (int phase = 0; phase < 2; ++phase){
    const bf16* A = phase ? A2 : A1;
    const bf16* B = phase ? B2 : B1;
    const int   K = phase ? H_ : C_;
    if (A == nullptr) continue;
    for (int k0 = 0; k0 < K; k0 += 32){
      #pragma unroll
      for (int i = 0; i < 2; ++i){
        const int c    = i*256 + wave*64 + lane;      // slot 0..511
        const int row  = c >> 2;
        const int jsrc = (c & 3) ^ ((c >> 3) & 3);
        int ar = m0 + row; if (ar >= M) ar = M - 1;
        gload_lds16(A + (size_t)ar*K + k0 + jsrc*8,         As + (size_t)c*8);
        gload_lds16(B + (size_t)(n0 + row)*K + k0 + jsrc*8, Bs + (size_t)c*8);
      }
      __syncthreads();
      short8 af[4], bfr[4];
      #pragma unroll
      for (int t = 0; t < 4; ++t){
        const int ra = wm + t*16 + lrow;
        const int rb = wn + t*16 + lrow;
        af[t]  = *(const short8*)&As[(ra*4 + (lk ^ ((ra >> 1) & 3)))*8];
        bfr[t] = *(const short8*)&Bs[(rb*4 + (lk ^ ((rb >> 1) & 3)))*8];
      }
      #pragma unroll
      for (int mt = 0; mt < 4; ++mt)
        #pragma unroll
        for (int nt = 0; nt < 4; ++nt)
          acc[mt][nt] = __builtin_amdgcn_mfma_f32_16x16x32_bf16(af[mt], bfr[nt], acc[mt][nt], 0, 0, 0);
      __syncthreads();
    }
  }

  // ---- register-resident pointwise: lane owns channel j, 16 rows; acc[mt][gate][r] ----
  const int j  = blockIdx.x*32 + (wave & 1)*16 + lrow;   // global channel in [0,H)
  const float bi = bsd[0*H_ + j], bff = bsd[1*H_ + j];
  const float bg = bsd[2*H_ + j], bo  = bsd[3*H_ + j];
  const float aw = awd[j];
  #pragma unroll
  for (int mt = 0; mt < 4; ++mt){
    #pragma unroll
    for (int r = 0; r < 4; ++r){
      const int row = m0 + wm + mt*16 + lk*4 + r;
      const bool ok = row < M;
      const size_t idx = (size_t)row*H_ + j;
      float co = 0.f;
      if (A2 && ok) co = __bfloat162float(cst[idx]);
      float ig = sigm_f(acc[mt][0][r] + bi);
      float fg = sigm_f(acc[mt][1][r] + bff);
      float gt = tanh_f(acc[mt][2][r] + bg);
      float og = sigm_f(acc[mt][3][r] + bo);
      float cv = fg*co + ig*gt;
      float hv = og*tanh_f(cv);
      if (ok && hout){                  // final step: h/c never read again -> skip stores
        cst[idx]  = __float2bfloat16(cv);
        hout[idx] = __float2bfloat16(hv);
      }
      float att = ok ? hv*aw : 0.f;
      att += __shfl_xor(att, 1);
      att += __shfl_xor(att, 2);
      att += __shfl_xor(att, 4);
      att += __shfl_xor(att, 8);
      if (lrow == 0 && ok) atomicAdd(&alpha[row], att);
    }
  }
}

// ============================ GMM layer pieces ============================
// edge weights in CSR order (easort is pre-sorted), bf16 output (16 B/edge)
__global__ void compute_w_k(const float* __restrict__ easort, const float* __restrict__ mu,
                            const float* __restrict__ sigma, bf16* __restrict__ wsrt)
{
  int e = blockIdx.x*256 + threadIdx.x;
  if (e >= E_) return;
  float2 a = ((const float2*)easort)[e];
  short8 o;
  #pragma unroll
  for (int k = 0; k < 8; k++){
    float d0 = a.x - mu[2*k],  d1 = a.y - mu[2*k+1];
    float s0 = sigma[2*k],     s1 = sigma[2*k+1];
    float t = -0.5f*(d0*d0/(1e-15f + s0*s0) + d1*d1/(1e-15f + s1*s1));
    o[k] = __builtin_bit_cast(short, __float2bfloat16(expf(t)));
  }
  *(short8*)(wsrt + (size_t)e*8) = o;
}

// t[d,k,:] = (1/deg_d) * sum_{e->d} w[e,k] * h[src_e,:]  -- wave per dst node.
__global__ __launch_bounds__(256)
void aggregate_t_k(const bf16* __restrict__ h, const bf16* __restrict__ wsrt,
                   const int* __restrict__ rowptr, const int* __restrict__ srcsort,
                   const float* __restrict__ degf, bf16* __restrict__ t)
{
  int node = blockIdx.x*4 + (threadIdx.x >> 6);
  int lane = threadIdx.x & 63;
  if (node >= N_) return;
  int p0 = rowptr[node], p1 = rowptr[node+1];
  float ax[8] = {}, ay[8] = {};
  for (int p = p0; p < p1; p++){
    int s = srcsort[p];
    short8 wv = *(const short8*)(wsrt + (size_t)p*8);
    float2 v = __bfloat1622float2(((const __hip_bfloat162*)(h + (size_t)s*C_))[lane]);
    #pragma unroll
    for (int k = 0; k < 8; k++){
      float wk = bf2f(wv[k]);
      ax[k] = fmaf(wk, v.x, ax[k]);
      ay[k] = fmaf(wk, v.y, ay[k]);
    }
  }
  float inv = 1.0f / degf[node];
  __hip_bfloat162* tp = (__hip_bfloat162*)(t + (size_t)node*(K_*C_));
  #pragma unroll
  for (int k = 0; k < 8; k++){
    __hip_bfloat162 o; o.x = __float2bfloat16(ax[k]*inv); o.y = __float2bfloat16(ay[k]*inv);
    tp[k*64 + lane] = o;
  }
}

__global__ void bn_apply_k(const float* __restrict__ hpre, const float* __restrict__ stats,
                           const float* __restrict__ gamma, const float* __restrict__ beta,
                           bf16* __restrict__ outp, int relu)
{
  int i = blockIdx.x*256 + threadIdx.x;
  if (i >= N_*C_) return;
  int c = i & 127;
  float mean = stats[c] * (1.0f/N_);
  float var  = stats[c+128] * (1.0f/N_) - mean*mean;
  float rstd = rsqrtf(var + 1e-5f);
  float v = (hpre[i] - mean)*rstd*gamma[c] + beta[c];
  if (relu) v = fmaxf(v, 0.f);
  outp[i] = __float2bfloat16(v);
}

// ============================ JK softmax + pooling ============================
__global__ void jk_pool_k(const float* __restrict__ x, const bf16* __restrict__ hlist,
                          const float* __restrict__ alpha, const int* __restrict__ batch,
                          float* __restrict__ hgraph, float* __restrict__ gcnt)
{
  int n = blockIdx.x, c = threadIdx.x;
  float a[5]; float mx = -1e30f;
  #pragma unroll
  for (int t = 0; t < 5; t++){ a[t] = alpha[(size_t)t*N_ + n]; mx = fmaxf(mx, a[t]); }
  float ssum = 0.f;
  #pragma unroll
  for (int t = 0; t < 5; t++){ a[t] = expf(a[t] - mx); ssum += a[t]; }
  float inv = 1.0f/ssum;
  float val = a[0]*inv*x[(size_t)n*C_ + c];
  #pragma unroll
  for (int t = 1; t < 5; t++)
    val = fmaf(a[t]*inv, __bfloat162float(hlist[((size_t)(t-1)*N_ + n)*C_ + c]), val);
  int bg = batch[n];
  atomicAdd(&hgraph[(size_t)bg*C_ + c], val);
  if (c == 0) atomicAdd(&gcnt[bg], 1.0f);
}

__global__ void pool_div_k(const float* __restrict__ hg, const float* __restrict__ gcnt,
                           bf16* __restrict__ hgb){
  int i = blockIdx.x*256 + threadIdx.x;
  if (i < B_*C_) hgb[i] = __float2bfloat16(hg[i] / fmaxf(gcnt[i >> 7], 1.0f));
}

// ============================ final LayerNorm ============================
__global__ __launch_bounds__(256)
void layernorm_k(float* __restrict__ z, const float* __restrict__ g, const float* __restrict__ b){
  int row = blockIdx.x, j = threadIdx.x;
  float v = z[(size_t)row*NOUT_ + j];
  float s = v, s2 = v*v;
  #pragma unroll
  for (int o = 32; o; o >>= 1){ s += __shfl_down(s, o); s2 += __shfl_down(s2, o); }
  __shared__ float sh[8];
  int w = j >> 6;
  if ((j & 63) == 0){ sh[w] = s; sh[4+w] = s2; }
  __syncthreads();
  float st  = sh[0] + sh[1] + sh[2] + sh[3];
  float st2 = sh[4] + sh[5] + sh[6] + sh[7];
  float mean = st * (1.0f/NOUT_);
  float var  = st2 * (1.0f/NOUT_) - mean*mean;
  float rstd = rsqrtf(var + 1e-5f);
  z[(size_t)row*NOUT_ + j] = (v - mean)*rstd*g[j] + b[j];
}

// ============================ launch ============================
extern "C" void kernel_launch(void* const* d_in, const int* in_sizes, int n_in,
                              void* d_out, int out_size, void* d_ws, size_t ws_size,
                              hipStream_t stream)
{
  (void)in_sizes; (void)n_in; (void)out_size; (void)ws_size;
  const float* x     = (const float*)d_in[0];
  const int*   eidx  = (const int*)  d_in[1];
  const float* eattr = (const float*)d_in[2];
  const int*   batch = (const int*)  d_in[3];
  const float* g     = (const float*)d_in[4];
  const float* root  = (const float*)d_in[5];
  const float* bias  = (const float*)d_in[6];
  const float* mu    = (const float*)d_in[7];
  const float* sigma = (const float*)d_in[8];
  const float* bng   = (const float*)d_in[9];
  const float* bnb   = (const float*)d_in[10];
  const float* w_ih  = (const float*)d_in[11];
  const float* w_hh  = (const float*)d_in[12];
  const float* b_ih  = (const float*)d_in[13];
  const float* b_hh  = (const float*)d_in[14];
  const float* attw  = (const float*)d_in[15];
  // d_in[16] = att_b: softmax-shift-invariant, unused
  const float* p1w   = (const float*)d_in[17];
  const float* p1b   = (const float*)d_in[18];
  const float* p2w   = (const float*)d_in[19];
  const float* p2b   = (const float*)d_in[20];
  const float* lng   = (const float*)d_in[21];
  const float* lnb   = (const float*)d_in[22];
  float* outp = (float*)d_out;

  const int* src = eidx;
  const int* dst = eidx + E_;

  // ---- workspace carve (~205 MB) ----
  size_t off = 0;
  char* wsb = (char*)d_ws;
  auto carve = [&](size_t bytes)->void*{ void* p = wsb + off; off = align256(off + bytes); return p; };
  bf16*  hlist  = (bf16*) carve((size_t)L_*N_*C_*2);        // 30.7 MB  h_list[1..4] bf16
  void*  big    =         carve((size_t)N_*(K_*C_)*2);      // 61.4 MB: t bf16
  void*  uni    =         carve((size_t)6*N_*H_*2 + 256);   // GMM: wsrt+hpre | LSTM: 2x(hA,hB,c)
  bf16*  xb     = (bf16*) carve((size_t)N_*C_*2);           // x in bf16
  float* alpha  = (float*)carve((size_t)(L_+1)*N_*4);
  float* hgraph = (float*)carve((size_t)B_*C_*4);
  bf16*  hgb    = (bf16*) carve((size_t)B_*C_*2);
  float* gcnt   = (float*)carve((size_t)B_*4);
  bf16*  z1b    = (bf16*) carve((size_t)B_*NHID_*2);
  float* bnstats= (float*)carve((size_t)L_*2*C_*4);
  float* degf   = (float*)carve((size_t)N_*4);
  int* cnt      = (int*)  carve((size_t)N_*4);
  int* rowptr   = (int*)  carve((size_t)(N_+1)*4);
  int* fill     = (int*)  carve((size_t)N_*4);
  int* srcsort  = (int*)  carve((size_t)E_*4);
  float* easort = (float*)carve((size_t)E_*2*4);
  int* btot     = (int*)  carve((size_t)(SCAN_B+1)*4);
  int* boff     = (int*)  carve((size_t)(SCAN_B+1)*4);
  // bf16 weights
  bf16* gGT   = (bf16*)carve((size_t)L_*C_*(K_*C_)*2);      // [L][c'][k*C+c] for t-GEMM
  bf16* rootT = (bf16*)carve((size_t)L_*C_*C_*2);           // [L][C, C]
  bf16* wihp  = (bf16*)carve((size_t)2*4*H_*C_*2);          // [2][1024][128] gate-permuted
  bf16* whhp  = (bf16*)carve((size_t)2*4*H_*H_*2);          // [2][1024][256] gate-permuted
  float* bsum = (float*)carve((size_t)2*4*H_*4);            // b_ih+b_hh, original order
  bf16* p1T   = (bf16*)carve((size_t)NHID_*C_*2);
  bf16* p2T   = (bf16*)carve((size_t)NOUT_*NHID_*2);

  // union aliases (GMM phase vs LSTM phase)
  bf16*  wsrt   = (bf16*)uni;                                // [E,8] bf16  7.7 MB
  float* hpre   = (float*)((char*)uni + (size_t)E_*K_*2);    // [N,C] fp32 15.4 MB
  bf16*  hAf    = (bf16*)uni;                                // per-dir h ping/pong + c, each [N,H] bf16
  bf16*  hAb    = hAf + (size_t)N_*H_;
  bf16*  hBf    = hAb + (size_t)N_*H_;
  bf16*  hBb    = hBf + (size_t)N_*H_;
  bf16*  csf    = hBb + (size_t)N_*H_;
  bf16*  csb    = csf + (size_t)N_*H_;
  bf16*  tbuf   = (bf16*)big;                                // [N,K*C] bf16

  // ---- zero-init (ws is poisoned every call) ----
  hipMemsetAsync(cnt,     0, (size_t)N_*4, stream);
  hipMemsetAsync(fill,    0, (size_t)N_*4, stream);
  hipMemsetAsync(bnstats, 0, (size_t)L_*2*C_*4, stream);
  hipMemsetAsync(hgraph,  0, (size_t)B_*C_*4, stream);
  hipMemsetAsync(gcnt,    0, (size_t)B_*4, stream);
  hipMemsetAsync(alpha,   0, (size_t)(L_+1)*N_*4, stream);

  const dim3 blk(256);

  // ---- CSR build ----
  hist_k  <<<(E_+255)/256, 256, 0, stream>>>(dst, cnt);
  scan1_k <<<SCAN_B, 1024, 0, stream>>>(cnt, rowptr, btot);
  scan2_k <<<1, 64, 0, stream>>>(btot, boff);
  scan3_k <<<SCAN_B, 1024, 0, stream>>>(rowptr, boff);
  degf_k  <<<(N_+255)/256, 256, 0, stream>>>(cnt, degf);
  scatter_k<<<(E_+255)/256, 256, 0, stream>>>(src, dst, eattr, rowptr, fill, srcsort, easort);

  // ---- weight/activation casts ----
  cast_k <<<(N_*C_+255)/256, blk, 0, stream>>>(x, xb, N_*C_);
  gtcast_k<<<dim3((C_*K_*C_)/256, L_), blk, 0, stream>>>(g, gGT);
  tcast_k<<<dim3((C_*C_+255)/256,   L_), blk, 0, stream>>>(root, rootT, C_,   C_);
  permcast_k<<<dim3((1024*C_+255)/256, 2), blk, 0, stream>>>(w_ih, wihp, C_);
  permcast_k<<<dim3((1024*H_+255)/256, 2), blk, 0, stream>>>(w_hh, whhp, H_);
  biassum_k<<<8, blk, 0, stream>>>(b_ih, b_hh, bsum);
  tcast_k<<<dim3((C_*NHID_+255)/256, 1), blk, 0, stream>>>(p1w, p1T, C_,    NHID_);
  tcast_k<<<dim3((NHID_*NOUT_+255)/256,1), blk, 0, stream>>>(p2w, p2T, NHID_, NOUT_);

  const int MB = (N_ + 127)/128;  // 235

  // ---- 4 GMMConv + BN layers (t-formulation, BK=64 GEMM, stats fused) ----
  for (int l = 0; l < L_; l++){
    const bf16* hin = l ? (hlist + (size_t)(l-1)*N_*C_) : xb;
    compute_w_k<<<(E_+255)/256, blk, 0, stream>>>(easort, mu + (size_t)l*K_*2, sigma + (size_t)l*K_*2, wsrt);
    aggregate_t_k<<<N_/4, blk, 0, stream>>>(hin, wsrt, rowptr, srcsort, degf, tbuf);
    gmm_gemm64_k<<<dim3(MB), blk, 0, stream>>>(
        tbuf, gGT + (size_t)l*C_*K_*C_, hin, rootT + (size_t)l*C_*C_,
        bias + (size_t)l*C_, hpre, bnstats + l*2*C_, N_);
    bn_apply_k<<<(N_*C_+255)/256, blk, 0, stream>>>(hpre, bnstats + l*2*C_, bng + (size_t)l*C_, bnb + (size_t)l*C_,
                                                    hlist + (size_t)l*N_*C_, (l < L_-1) ? 1 : 0);
  }

  // ---- bidirectional JK-LSTM over xs = [x, h1..h4] (T=5), both dirs per dispatch ----
  {
    const bf16 *hpf = nullptr, *hpb = nullptr;
    for (int s = 0; s < 5; s++){
      int tf = s, tb = 4 - s;
      const bf16* xtf = tf ? (hlist + (size_t)(tf-1)*N_*C_) : xb;
      const bf16* xtb = tb ? (hlist + (size_t)(tb-1)*N_*C_) : xb;
      bf16* hof = (s == 4) ? nullptr : ((s & 1) ? hBf : hAf);
      bf16* hob = (s == 4) ? nullptr : ((s & 1) ? hBb : hAb);
      lstm_step2_k<<<dim3(8, MB, 2), blk, 0, stream>>>(
          xtf, xtb, wihp, whhp, hpf, hpb, bsum, hof, hob, csf, csb,
          attw, alpha + (size_t)tf*N_, alpha + (size_t)tb*N_, N_);
      hpf = hof; hpb = hob;
    }
  }

  // ---- JK attention softmax + weighted sum + global mean pool ----
  jk_pool_k<<<N_, 128, 0, stream>>>(x, hlist, alpha, batch, hgraph, gcnt);
  pool_div_k<<<(B_*C_+255)/256, blk, 0, stream>>>(hgraph, gcnt, hgb);

  // ---- MLP head + LayerNorm ----
  gemm_bf16_k<1><<<dim3(NHID_/128, B_/128), blk, 0, stream>>>(
      hgb, p1T, C_, nullptr, nullptr, 0, p1b, z1b, B_, NHID_, 1);
  gemm_bf16_k<0><<<dim3(NOUT_/128, B_/128), blk, 0, stream>>>(
      z1b, p2T, NHID_, nullptr, nullptr, 0, p2b, outp, B_, NOUT_, 0);
  layernorm_k<<<B_, 256, 0, stream>>>(outp, lng, lnb);
}

// Round 13
// 1193.810 us; speedup vs baseline: 1.2891x; 1.0161x over previous
//
#include <hip/hip_runtime.h>
#include <hip/hip_bf16.h>
#include <math.h>

#define N_    30000
#define E_    480000
#define C_    128
#define K_    8
#define L_    4
#define H_    256
#define NHID_ 512
#define NOUT_ 256
#define B_    1024
#define SCAN_B 30   // ceil(N_/1024)

typedef __attribute__((ext_vector_type(8))) short short8;
typedef __attribute__((ext_vector_type(4))) float floatx4;
typedef __hip_bfloat16 bf16;

static inline size_t align256(size_t x){ return (x + 255) & ~(size_t)255; }

__device__ __forceinline__ void gload_lds16(const void* g, void* l){
  __builtin_amdgcn_global_load_lds((const __attribute__((address_space(1))) void*)g,
                                   (__attribute__((address_space(3))) void*)l, 16, 0, 0);
}
__device__ __forceinline__ float bf2f(short s){
  union { unsigned u; float f; } x; x.u = ((unsigned)(unsigned short)s) << 16; return x.f;
}
// fast sigmoid/tanh: v_exp-based, ~1e-5 rel err (negligible vs bf16 rounding)
__device__ __forceinline__ float sigm_f(float x){ return __builtin_amdgcn_rcpf(1.f + __expf(-x)); }
__device__ __forceinline__ float tanh_f(float x){ return 1.f - 2.f*__builtin_amdgcn_rcpf(1.f + __expf(2.f*x)); }

// ============================ CSR build ============================
__global__ void hist_k(const int* __restrict__ dst, int* __restrict__ cnt){
  int e = blockIdx.x*256 + threadIdx.x;
  if (e < E_) atomicAdd(&cnt[dst[e]], 1);
}

// scan + degf fused (cnt already in hand)
__global__ void scan1_k(const int* __restrict__ cnt, int* __restrict__ rowptr,
                        int* __restrict__ btot, float* __restrict__ degf){
  __shared__ int sh[1024];
  int i = blockIdx.x*1024 + (int)threadIdx.x;
  int v = (i < N_) ? cnt[i] : 0;
  if (i < N_) degf[i] = fmaxf((float)v, 1.0f);
  sh[threadIdx.x] = v;
  __syncthreads();
  for (int o = 1; o < 1024; o <<= 1){
    int t = (threadIdx.x >= (unsigned)o) ? sh[threadIdx.x - o] : 0;
    __syncthreads();
    sh[threadIdx.x] += t;
    __syncthreads();
  }
  if (i < N_) rowptr[i] = sh[threadIdx.x] - v;
  if (threadIdx.x == 1023) btot[blockIdx.x] = sh[1023];
}
__global__ void scan2_k(const int* __restrict__ btot, int* __restrict__ boff){
  if (threadIdx.x == 0){
    int s = 0;
    for (int b = 0; b < SCAN_B; b++){ boff[b] = s; s += btot[b]; }
    boff[SCAN_B] = s;
  }
}
__global__ void scan3_k(int* __restrict__ rowptr, const int* __restrict__ boff){
  int i = blockIdx.x*1024 + (int)threadIdx.x;
  if (i < N_) rowptr[i] += boff[blockIdx.x];
  if (i == N_-1) rowptr[N_] = boff[SCAN_B];
}

// also scatters edge_attr into CSR order (so compute_w needs no indirection)
__global__ void scatter_k(const int* __restrict__ src, const int* __restrict__ dst,
                          const float* __restrict__ ea,
                          const int* __restrict__ rowptr, int* __restrict__ fill,
                          int* __restrict__ srcsort, float* __restrict__ easort){
  int e = blockIdx.x*256 + threadIdx.x;
  if (e >= E_) return;
  int d = dst[e];
  int pos = rowptr[d] + atomicAdd(&fill[d], 1);
  srcsort[pos] = src[e];
  ((float2*)easort)[pos] = ((const float2*)ea)[e];
}

// ============================ casts ============================
__global__ void cast_k(const float* __restrict__ in, bf16* __restrict__ out, int n){
  int i = blockIdx.x*256 + threadIdx.x;
  if (i < n) out[i] = __float2bfloat16(in[i]);
}
// in: [batch][R][Cc] fp32 -> out: [batch][Cc][R] bf16 (N x K layout for GEMM B^T)
__global__ void tcast_k(const float* __restrict__ in, bf16* __restrict__ out, int R, int Cc){
  const float* ip = in + (size_t)blockIdx.y*R*Cc;
  bf16* op = out + (size_t)blockIdx.y*R*Cc;
  int i = blockIdx.x*256 + threadIdx.x;
  if (i >= R*Cc) return;
  int c = i / R, r = i - c*R;
  op[i] = __float2bfloat16(ip[(size_t)r*Cc + c]);
}
// g[l]: [C, K*C] -> gGT[l]: [c'][k*C+c] = g[c][k*C+c']   (B^T layout for t-GEMM)
__global__ void gtcast_k(const float* __restrict__ in, bf16* __restrict__ out){
  const float* ip = in + (size_t)blockIdx.y*C_*(K_*C_);
  bf16* op = out + (size_t)blockIdx.y*C_*(K_*C_);
  int i = blockIdx.x*256 + threadIdx.x;   // < 131072
  int co = i >> 10;
  int rem = i & 1023;
  int k = rem >> 7, c = rem & 127;
  op[i] = __float2bfloat16(ip[(size_t)c*(K_*C_) + k*C_ + co]);
}
// LSTM weights: permute gate rows so within each wave's 64 cols, nt==gate, lrow==channel.
// pi(r): gate=r>>8, j=r&255 -> (j>>5)*128 + ((j>>4)&1)*64 + gate*16 + (j&15)
__global__ void permcast_k(const float* __restrict__ in, bf16* __restrict__ out, int Kdim){
  const float* ip = in + (size_t)blockIdx.y*1024*Kdim;
  bf16* op = out + (size_t)blockIdx.y*1024*Kdim;
  int i = blockIdx.x*256 + threadIdx.x;
  if (i >= 1024*Kdim) return;
  int r = i / Kdim, k = i - r*Kdim;
  int gsel = r >> 8, jj = r & 255;
  int p = ((jj >> 5) << 7) + (((jj >> 4) & 1) << 6) + (gsel << 4) + (jj & 15);
  op[(size_t)p*Kdim + k] = __float2bfloat16(ip[i]);
}
__global__ void biassum_k(const float* __restrict__ bih, const float* __restrict__ bhh,
                          float* __restrict__ bs){
  int i = blockIdx.x*256 + threadIdx.x;  // < 2048, original gate-major order
  if (i < 2048) bs[i] = bih[i] + bhh[i];
}

// ============================ bf16 MFMA GEMM (generic, BK=32, xor-swizzled LDS) ============
// Staging slot c holds row=c>>2, chunk j=(c&3)^((c>>3)&3): coalesced 64B-contiguous global
// reads per row, and fragment reads at slot row*4+(lk^((row>>1)&3)) are 2 lanes/bank (free).
// C[M,Nn] = A1[M,K1] @ B1[Nn,K1]^T (+ A2[M,K2] @ B2[Nn,K2]^T) (+bias1) (relu)
template<int OUTBF16>
__global__ __launch_bounds__(256)
void gemm_bf16_k(const bf16* __restrict__ A1, const bf16* __restrict__ B1, int K1,
                 const bf16* __restrict__ A2, const bf16* __restrict__ B2, int K2,
                 const float* __restrict__ bias1,
                 void* __restrict__ Cout, int M, int Nn, int relu)
{
  __shared__ short As[128*32];
  __shared__ short Bs[128*32];
  const int tid  = threadIdx.x;
  const int wave = tid >> 6, lane = tid & 63;
  const int m0 = blockIdx.y*128, n0 = blockIdx.x*128;
  const int wm = (wave >> 1)*64, wn = (wave & 1)*64;
  const int lrow = lane & 15, lk = lane >> 4;
  floatx4 acc[4][4] = {};

  #pragma unroll
  for (int phase = 0; phase < 2; ++phase){
    const bf16* A = phase ? A2 : A1;
    const bf16* B = phase ? B2 : B1;
    const int   K = phase ? K2 : K1;
    if (A == nullptr) continue;
    for (int k0 = 0; k0 < K; k0 += 32){
      #pragma unroll
      for (int i = 0; i < 2; ++i){
        const int c    = i*256 + wave*64 + lane;
        const int row  = c >> 2;
        const int jsrc = (c & 3) ^ ((c >> 3) & 3);
        int ar = m0 + row; if (ar >= M) ar = M - 1;
        gload_lds16(A + (size_t)ar*K + k0 + jsrc*8,         As + (size_t)c*8);
        gload_lds16(B + (size_t)(n0 + row)*K + k0 + jsrc*8, Bs + (size_t)c*8);
      }
      __syncthreads();
      short8 af[4], bfr[4];
      #pragma unroll
      for (int t = 0; t < 4; ++t){
        const int ra = wm + t*16 + lrow;
        const int rb = wn + t*16 + lrow;
        af[t]  = *(const short8*)&As[(ra*4 + (lk ^ ((ra >> 1) & 3)))*8];
        bfr[t] = *(const short8*)&Bs[(rb*4 + (lk ^ ((rb >> 1) & 3)))*8];
      }
      #pragma unroll
      for (int mt = 0; mt < 4; ++mt)
        #pragma unroll
        for (int nt = 0; nt < 4; ++nt)
          acc[mt][nt] = __builtin_amdgcn_mfma_f32_16x16x32_bf16(af[mt], bfr[nt], acc[mt][nt], 0, 0, 0);
      __syncthreads();
    }
  }

  float* outf = (float*)Cout;
  bf16*  outb = (bf16*)Cout;
  #pragma unroll
  for (int nt = 0; nt < 4; ++nt){
    const int col = n0 + wn + nt*16 + lrow;
    float bv = bias1 ? bias1[col] : 0.f;
    #pragma unroll
    for (int mt = 0; mt < 4; ++mt){
      #pragma unroll
      for (int r = 0; r < 4; ++r){
        const int row = m0 + wm + mt*16 + lk*4 + r;   // C/D: col=lane&15, row=(lane>>4)*4+reg
        if (row >= M) continue;
        float v = acc[mt][nt][r] + bv;
        if (relu) v = fmaxf(v, 0.f);
        if (OUTBF16) outb[(size_t)row*Nn + col] = __float2bfloat16(v);
        else         outf[(size_t)row*Nn + col] = v;
      }
    }
  }
}

// ============================ GMM GEMM, 64-row tiles, BK=64, stats fused ============================
// hpre = t@G_stacked(K=1024) + h@root(K=128) + bias. 64x128 tile -> 469 blocks (~1.8/CU vs
// 235 at 128-row): the GMM grid is under-subscribed, so doubling independent fetch streams
// is pure gain (inverse of the r7/r8/r11 lesson — no co-residency to lose, only to create).
// 4 waves x (64m x 32n) each. BK=64 xor swizzle: slot c holds row=c>>3, chunk (c&7)^(row&7)
// -> each row sources one contiguous 128B (coalesced); fragment reads 2 lanes/bank.
// Same k-order as r12 -> bit-identical. Per-column sum/sumsq fused into stats.
__global__ __launch_bounds__(256)
void gmm_gemm64_k(const bf16* __restrict__ tbuf, const bf16* __restrict__ gGTl,
                  const bf16* __restrict__ hin, const bf16* __restrict__ rootTl,
                  const float* __restrict__ bias, float* __restrict__ outp,
                  float* __restrict__ stats, int M)
{
  __shared__ short As[64*64];    // 8 KB
  __shared__ short Bs[128*64];   // 16 KB
  __shared__ float colstat[256];
  const int tid  = threadIdx.x;
  const int wave = tid >> 6, lane = tid & 63;
  const int m0 = blockIdx.x*64;
  const int wn = wave*32;
  const int lrow = lane & 15, lk = lane >> 4;
  floatx4 acc[4][2] = {};
  colstat[tid] = 0.f;

  #pragma unroll
  for (int phase = 0; phase < 2; ++phase){
    const bf16* A  = phase ? hin    : tbuf;
    const bf16* B  = phase ? rootTl : gGTl;
    const int   ld = phase ? C_     : (K_*C_);
    const int   K  = phase ? C_     : (K_*C_);
    for (int k0 = 0; k0 < K; k0 += 64){
      // 512 A-chunks + 1024 B-chunks = 1536; 6 iters x 4 waves x 64 lanes; wave-uniform split.
      #pragma unroll
      for (int i = 0; i < 6; ++i){
        const int t = i*256 + wave*64 + lane;
        if (t < 512){
          const int c = t, row = c >> 3, jsrc = (c & 7) ^ (row & 7);
          int ar = m0 + row; if (ar >= M) ar = M - 1;
          gload_lds16(A + (size_t)ar*ld + k0 + jsrc*8, As + (size_t)c*8);
        } else {
          const int c = t - 512, row = c >> 3, jsrc = (c & 7) ^ (row & 7);
          gload_lds16(B + (size_t)row*ld + k0 + jsrc*8, Bs + (size_t)c*8);
        }
      }
      __syncthreads();
      #pragma unroll
      for (int kk = 0; kk < 2; ++kk){
        short8 af[4], bfr[2];
        #pragma unroll
        for (int t = 0; t < 4; ++t){
          const int ra = t*16 + lrow;
          af[t] = *(const short8*)&As[(ra*8 + ((kk*4 + lk) ^ (ra & 7)))*8];
        }
        #pragma unroll
        for (int u = 0; u < 2; ++u){
          const int rb = wn + u*16 + lrow;
          bfr[u] = *(const short8*)&Bs[(rb*8 + ((kk*4 + lk) ^ (rb & 7)))*8];
        }
        #pragma unroll
        for (int mt = 0; mt < 4; ++mt)
          #pragma unroll
          for (int u = 0; u < 2; ++u)
            acc[mt][u] = __builtin_amdgcn_mfma_f32_16x16x32_bf16(af[mt], bfr[u], acc[mt][u], 0, 0, 0);
      }
      __syncthreads();
    }
  }

  #pragma unroll
  for (int u = 0; u < 2; ++u){
    const int col = wn + u*16 + lrow;
    const float bv = bias[col];
    float s = 0.f, s2 = 0.f;
    #pragma unroll
    for (int mt = 0; mt < 4; ++mt){
      #pragma unroll
      for (int r = 0; r < 4; ++r){
        const int row = m0 + mt*16 + lk*4 + r;
        if (row >= M) continue;
        float v = acc[mt][u][r] + bv;
        outp[(size_t)row*C_ + col] = v;
        s += v; s2 += v*v;
      }
    }
    s  += __shfl_down(s, 16);  s  += __shfl_down(s, 32);
    s2 += __shfl_down(s2, 16); s2 += __shfl_down(s2, 32);
    if (lane < 16){
      atomicAdd(&colstat[col], s);
      atomicAdd(&colstat[128 + col], s2);
    }
  }
  __syncthreads();
  if (tid < 128){
    atomicAdd(&stats[tid],       colstat[tid]);
    atomicAdd(&stats[128 + tid], colstat[128 + tid]);
  }
}

// ============================ fused LSTM step, both directions ============================
// r6/r10 grid (8 n-tiles fastest, 235 m-tiles, 2 dirs): the 8 A-tile sharers are temporally
// concurrent on 8 XCDs = 8 independent HBM miss streams (max MLP — r7/r8/r11 variants that
// reduced concurrent fetchers all lost). BK=32 xor-swizzled LDS: coalesced, zero conflicts.
// Weights permuted so nt==gate, lrow==channel: pointwise LSTM in registers. c-state bf16.
// hpf/hpb==nullptr -> step 0 (h=c=0). hof==nullptr -> final step (h/c outputs never read).
__global__ __launch_bounds__(256)
void lstm_step2_k(const bf16* __restrict__ A1f, const bf16* __restrict__ A1b,
                  const bf16* __restrict__ wihp, const bf16* __restrict__ whhp,
                  const bf16* __restrict__ hpf, const bf16* __restrict__ hpb,
                  const float* __restrict__ bsum,   // [2][4][H] combined bias
                  bf16* __restrict__ hof, bf16* __restrict__ hob,
                  bf16* __restrict__ csf, bf16* __restrict__ csb,
                  const float* __restrict__ attw,   // [2][H]
                  float* __restrict__ alf, float* __restrict__ alb,
                  int M)
{
  __shared__ short As[128*32];
  __shared__ short Bs[128*32];
  const int dir = blockIdx.z;
  const bf16* A1 = dir ? A1b : A1f;
  const bf16* A2 = dir ? hpb : hpf;
  const bf16* B1 = wihp + (size_t)dir*4*H_*C_;
  const bf16* B2 = whhp + (size_t)dir*4*H_*H_;
  bf16* hout = dir ? hob : hof;
  bf16* cst  = dir ? csb : csf;
  float* alpha = dir ? alb : alf;
  const float* bsd = bsum + (size_t)dir*4*H_;
  const float* awd = attw + (size_t)dir*H_;

  const int tid  = threadIdx.x;
  const int wave = tid >> 6, lane = tid & 63;
  const int m0 = blockIdx.y*128, n0 = blockIdx.x*128;
  const int wm = (wave >> 1)*64, wn = (wave & 1)*64;
  const int lrow = lane & 15, lk = lane >> 4;
  floatx4 acc[4][4] = {};

  #pragma unroll
  for (int phase = 0; phase < 2; ++phase){
    const bf16* A = phase ? A2 : A1;
    const bf16* B = phase ? B2 : B1;
    const int   K = phase ? H_ : C_;
    if (A == nullptr) continue;
    for (int k0 = 0; k0 < K; k0 += 32){
      #pragma unroll
      for (int i = 0; i < 2; ++i){
        const int c    = i*256 + wave*64 + lane;      // slot 0..511
        const int row  = c >> 2;
        const int jsrc = (c & 3) ^ ((c >> 3) & 3);
        int ar = m0 + row; if (ar >= M) ar = M - 1;
        gload_lds16(A + (size_t)ar*K + k0 + jsrc*8,         As + (size_t)c*8);
        gload_lds16(B + (size_t)(n0 + row)*K + k0 + jsrc*8, Bs + (size_t)c*8);
      }
      __syncthreads();
      short8 af[4], bfr[4];
      #pragma unroll
      for (int t = 0; t < 4; ++t){
        const int ra = wm + t*16 + lrow;
        const int rb = wn + t*16 + lrow;
        af[t]  = *(const short8*)&As[(ra*4 + (lk ^ ((ra >> 1) & 3)))*8];
        bfr[t] = *(const short8*)&Bs[(rb*4 + (lk ^ ((rb >> 1) & 3)))*8];
      }
      #pragma unroll
      for (int mt = 0; mt < 4; ++mt)
        #pragma unroll
        for (int nt = 0; nt < 4; ++nt)
          acc[mt][nt] = __builtin_amdgcn_mfma_f32_16x16x32_bf16(af[mt], bfr[nt], acc[mt][nt], 0, 0, 0);
      __syncthreads();
    }
  }

  // ---- register-resident pointwise: lane owns channel j, 16 rows; acc[mt][gate][r] ----
  const int j  = blockIdx.x*32 + (wave & 1)*16 + lrow;   // global channel in [0,H)
  const float bi = bsd[0*H_ + j], bff = bsd[1*H_ + j];
  const float bg = bsd[2*H_ + j], bo  = bsd[3*H_ + j];
  const float aw = awd[j];
  #pragma unroll
  for (int mt = 0; mt < 4; ++mt){
    #pragma unroll
    for (int r = 0; r < 4; ++r){
      const int row = m0 + wm + mt*16 + lk*4 + r;
      const bool ok = row < M;
      const size_t idx = (size_t)row*H_ + j;
      float co = 0.f;
      if (A2 && ok) co = __bfloat162float(cst[idx]);
      float ig = sigm_f(acc[mt][0][r] + bi);
      float fg = sigm_f(acc[mt][1][r] + bff);
      float gt = tanh_f(acc[mt][2][r] + bg);
      float og = sigm_f(acc[mt][3][r] + bo);
      float cv = fg*co + ig*gt;
      float hv = og*tanh_f(cv);
      if (ok && hout){                  // final step: h/c never read again -> skip stores
        cst[idx]  = __float2bfloat16(cv);
        hout[idx] = __float2bfloat16(hv);
      }
      float att = ok ? hv*aw : 0.f;
      att += __shfl_xor(att, 1);
      att += __shfl_xor(att, 2);
      att += __shfl_xor(att, 4);
      att += __shfl_xor(att, 8);
      if (lrow == 0 && ok) atomicAdd(&alpha[row], att);
    }
  }
}

// ============================ GMM layer pieces ============================
// edge weights for ALL 4 layers in one pass (easort read once), CSR order, bf16
__global__ void compute_w4_k(const float* __restrict__ easort, const float* __restrict__ mu,
                             const float* __restrict__ sigma, bf16* __restrict__ wsrt4)
{
  int e = blockIdx.x*256 + threadIdx.x;
  if (e >= E_) return;
  float2 a = ((const float2*)easort)[e];
  #pragma unroll
  for (int l = 0; l < L_; l++){
    short8 o;
    #pragma unroll
    for (int k = 0; k < 8; k++){
      float d0 = a.x - mu[l*16 + 2*k],  d1 = a.y - mu[l*16 + 2*k+1];
      float s0 = sigma[l*16 + 2*k],     s1 = sigma[l*16 + 2*k+1];
      float t = -0.5f*(d0*d0/(1e-15f + s0*s0) + d1*d1/(1e-15f + s1*s1));
      o[k] = __builtin_bit_cast(short, __float2bfloat16(expf(t)));
    }
    *(short8*)(wsrt4 + ((size_t)l*E_ + e)*8) = o;
  }
}

// t[d,k,:] = (1/deg_d) * sum_{e->d} w[e,k] * h[src_e,:]  -- wave per dst node.
__global__ __launch_bounds__(256)
void aggregate_t_k(const bf16* __restrict__ h, const bf16* __restrict__ wsrt,
                   const int* __restrict__ rowptr, const int* __restrict__ srcsort,
                   const float* __restrict__ degf, bf16* __restrict__ t)
{
  int node = blockIdx.x*4 + (threadIdx.x >> 6);
  int lane = threadIdx.x & 63;
  if (node >= N_) return;
  int p0 = rowptr[node], p1 = rowptr[node+1];
  float ax[8] = {}, ay[8] = {};
  for (int p = p0; p < p1; p++){
    int s = srcsort[p];
    short8 wv = *(const short8*)(wsrt + (size_t)p*8);
    float2 v = __bfloat1622float2(((const __hip_bfloat162*)(h + (size_t)s*C_))[lane]);
    #pragma unroll
    for (int k = 0; k < 8; k++){
      float wk = bf2f(wv[k]);
      ax[k] = fmaf(wk, v.x, ax[k]);
      ay[k] = fmaf(wk, v.y, ay[k]);
    }
  }
  float inv = 1.0f / degf[node];
  __hip_bfloat162* tp = (__hip_bfloat162*)(t + (size_t)node*(K_*C_));
  #pragma unroll
  for (int k = 0; k < 8; k++){
    __hip_bfloat162 o; o.x = __float2bfloat16(ax[k]*inv); o.y = __float2bfloat16(ay[k]*inv);
    tp[k*64 + lane] = o;
  }
}

__global__ void bn_apply_k(const float* __restrict__ hpre, const float* __restrict__ stats,
                           const float* __restrict__ gamma, const float* __restrict__ beta,
                           bf16* __restrict__ outp, int relu)
{
  int i = blockIdx.x*256 + threadIdx.x;
  if (i >= N_*C_) return;
  int c = i & 127;
  float mean = stats[c] * (1.0f/N_);
  float var  = stats[c+128] * (1.0f/N_) - mean*mean;
  float rstd = rsqrtf(var + 1e-5f);
  float v = (hpre[i] - mean)*rstd*gamma[c] + beta[c];
  if (relu) v = fmaxf(v, 0.f);
  outp[i] = __float2bfloat16(v);
}

// ============================ JK softmax + pooling ============================
__global__ void jk_pool_k(const float* __restrict__ x, const bf16* __restrict__ hlist,
                          const float* __restrict__ alpha, const int* __restrict__ batch,
                          float* __restrict__ hgraph, float* __restrict__ gcnt)
{
  int n = blockIdx.x, c = threadIdx.x;
  float a[5]; float mx = -1e30f;
  #pragma unroll
  for (int t = 0; t < 5; t++){ a[t] = alpha[(size_t)t*N_ + n]; mx = fmaxf(mx, a[t]); }
  float ssum = 0.f;
  #pragma unroll
  for (int t = 0; t < 5; t++){ a[t] = expf(a[t] - mx); ssum += a[t]; }
  float inv = 1.0f/ssum;
  float val = a[0]*inv*x[(size_t)n*C_ + c];
  #pragma unroll
  for (int t = 1; t < 5; t++)
    val = fmaf(a[t]*inv, __bfloat162float(hlist[((size_t)(t-1)*N_ + n)*C_ + c]), val);
  int bg = batch[n];
  atomicAdd(&hgraph[(size_t)bg*C_ + c], val);
  if (c == 0) atomicAdd(&gcnt[bg], 1.0f);
}

__global__ void pool_div_k(const float* __restrict__ hg, const float* __restrict__ gcnt,
                           bf16* __restrict__ hgb){
  int i = blockIdx.x*256 + threadIdx.x;
  if (i < B_*C_) hgb[i] = __float2bfloat16(hg[i] / fmaxf(gcnt[i >> 7], 1.0f));
}

// ============================ final LayerNorm ============================
__global__ __launch_bounds__(256)
void layernorm_k(float* __restrict__ z, const float* __restrict__ g, const float* __restrict__ b){
  int row = blockIdx.x, j = threadIdx.x;
  float v = z[(size_t)row*NOUT_ + j];
  float s = v, s2 = v*v;
  #pragma unroll
  for (int o = 32; o; o >>= 1){ s += __shfl_down(s, o); s2 += __shfl_down(s2, o); }
  __shared__ float sh[8];
  int w = j >> 6;
  if ((j & 63) == 0){ sh[w] = s; sh[4+w] = s2; }
  __syncthreads();
  float st  = sh[0] + sh[1] + sh[2] + sh[3];
  float st2 = sh[4] + sh[5] + sh[6] + sh[7];
  float mean = st * (1.0f/NOUT_);
  float var  = st2 * (1.0f/NOUT_) - mean*mean;
  float rstd = rsqrtf(var + 1e-5f);
  z[(size_t)row*NOUT_ + j] = (v - mean)*rstd*g[j] + b[j];
}

// ============================ launch ============================
extern "C" void kernel_launch(void* const* d_in, const int* in_sizes, int n_in,
                              void* d_out, int out_size, void* d_ws, size_t ws_size,
                              hipStream_t stream)
{
  (void)in_sizes; (void)n_in; (void)out_size; (void)ws_size;
  const float* x     = (const float*)d_in[0];
  const int*   eidx  = (const int*)  d_in[1];
  const float* eattr = (const float*)d_in[2];
  const int*   batch = (const int*)  d_in[3];
  const float* g     = (const float*)d_in[4];
  const float* root  = (const float*)d_in[5];
  const float* bias  = (const float*)d_in[6];
  const float* mu    = (const float*)d_in[7];
  const float* sigma = (const float*)d_in[8];
  const float* bng   = (const float*)d_in[9];
  const float* bnb   = (const float*)d_in[10];
  const float* w_ih  = (const float*)d_in[11];
  const float* w_hh  = (const float*)d_in[12];
  const float* b_ih  = (const float*)d_in[13];
  const float* b_hh  = (const float*)d_in[14];
  const float* attw  = (const float*)d_in[15];
  // d_in[16] = att_b: softmax-shift-invariant, unused
  const float* p1w   = (const float*)d_in[17];
  const float* p1b   = (const float*)d_in[18];
  const float* p2w   = (const float*)d_in[19];
  const float* p2b   = (const float*)d_in[20];
  const float* lng   = (const float*)d_in[21];
  const float* lnb   = (const float*)d_in[22];
  float* outp = (float*)d_out;

  const int* src = eidx;
  const int* dst = eidx + E_;

  // ---- workspace carve (~205 MB) ----
  size_t off = 0;
  char* wsb = (char*)d_ws;
  auto carve = [&](size_t bytes)->void*{ void* p = wsb + off; off = align256(off + bytes); return p; };
  bf16*  hlist  = (bf16*) carve((size_t)L_*N_*C_*2);        // 30.7 MB  h_list[1..4] bf16
  void*  big    =         carve((size_t)N_*(K_*C_)*2);      // 61.4 MB: t bf16
  void*  uni    =         carve((size_t)6*N_*H_*2 + 256);   // GMM: wsrt4(30.7)+hpre(15.4) | LSTM: 2x(hA,hB,c) 92MB
  bf16*  xb     = (bf16*) carve((size_t)N_*C_*2);           // x in bf16
  float* alpha  = (float*)carve((size_t)(L_+1)*N_*4);
  float* hgraph = (float*)carve((size_t)B_*C_*4);
  bf16*  hgb    = (bf16*) carve((size_t)B_*C_*2);
  float* gcnt   = (float*)carve((size_t)B_*4);
  bf16*  z1b    = (bf16*) carve((size_t)B_*NHID_*2);
  float* bnstats= (float*)carve((size_t)L_*2*C_*4);
  float* degf   = (float*)carve((size_t)N_*4);
  int* cnt      = (int*)  carve((size_t)N_*4);
  int* rowptr   = (int*)  carve((size_t)(N_+1)*4);
  int* fill     = (int*)  carve((size_t)N_*4);
  int* srcsort  = (int*)  carve((size_t)E_*4);
  float* easort = (float*)carve((size_t)E_*2*4);
  int* btot     = (int*)  carve((size_t)(SCAN_B+1)*4);
  int* boff     = (int*)  carve((size_t)(SCAN_B+1)*4);
  // bf16 weights
  bf16* gGT   = (bf16*)carve((size_t)L_*C_*(K_*C_)*2);      // [L][c'][k*C+c] for t-GEMM
  bf16* rootT = (bf16*)carve((size_t)L_*C_*C_*2);           // [L][C, C]
  bf16* wihp  = (bf16*)carve((size_t)2*4*H_*C_*2);          // [2][1024][128] gate-permuted
  bf16* whhp  = (bf16*)carve((size_t)2*4*H_*H_*2);          // [2][1024][256] gate-permuted
  float* bsum = (float*)carve((size_t)2*4*H_*4);            // b_ih+b_hh, original order
  bf16* p1T   = (bf16*)carve((size_t)NHID_*C_*2);
  bf16* p2T   = (bf16*)carve((size_t)NOUT_*NHID_*2);

  // union aliases (GMM phase vs LSTM phase)
  bf16*  wsrt4  = (bf16*)uni;                                // [4][E,8] bf16  30.7 MB
  float* hpre   = (float*)((char*)uni + (size_t)L_*E_*K_*2); // [N,C] fp32 15.4 MB
  bf16*  hAf    = (bf16*)uni;                                // per-dir h ping/pong + c, each [N,H] bf16
  bf16*  hAb    = hAf + (size_t)N_*H_;
  bf16*  hBf    = hAb + (size_t)N_*H_;
  bf16*  hBb    = hBf + (size_t)N_*H_;
  bf16*  csf    = hBb + (size_t)N_*H_;
  bf16*  csb    = csf + (size_t)N_*H_;
  bf16*  tbuf   = (bf16*)big;                                // [N,K*C] bf16

  // ---- zero-init (ws is poisoned every call) ----
  hipMemsetAsync(cnt,     0, (size_t)N_*4, stream);
  hipMemsetAsync(fill,    0, (size_t)N_*4, stream);
  hipMemsetAsync(bnstats, 0, (size_t)L_*2*C_*4, stream);
  hipMemsetAsync(hgraph,  0, (size_t)B_*C_*4, stream);
  hipMemsetAsync(gcnt,    0, (size_t)B_*4, stream);
  hipMemsetAsync(alpha,   0, (size_t)(L_+1)*N_*4, stream);

  const dim3 blk(256);

  // ---- CSR build ----
  hist_k  <<<(E_+255)/256, 256, 0, stream>>>(dst, cnt);
  scan1_k <<<SCAN_B, 1024, 0, stream>>>(cnt, rowptr, btot, degf);
  scan2_k <<<1, 64, 0, stream>>>(btot, boff);
  scan3_k <<<SCAN_B, 1024, 0, stream>>>(rowptr, boff);
  scatter_k<<<(E_+255)/256, 256, 0, stream>>>(src, dst, eattr, rowptr, fill, srcsort, easort);

  // ---- weight/activation casts ----
  cast_k <<<(N_*C_+255)/256, blk, 0, stream>>>(x, xb, N_*C_);
  gtcast_k<<<dim3((C_*K_*C_)/256, L_), blk, 0, stream>>>(g, gGT);
  tcast_k<<<dim3((C_*C_+255)/256,   L_), blk, 0, stream>>>(root, rootT, C_,   C_);
  permcast_k<<<dim3((1024*C_+255)/256, 2), blk, 0, stream>>>(w_ih, wihp, C_);
  permcast_k<<<dim3((1024*H_+255)/256, 2), blk, 0, stream>>>(w_hh, whhp, H_);
  biassum_k<<<8, blk, 0, stream>>>(b_ih, b_hh, bsum);
  tcast_k<<<dim3((C_*NHID_+255)/256, 1), blk, 0, stream>>>(p1w, p1T, C_,    NHID_);
  tcast_k<<<dim3((NHID_*NOUT_+255)/256,1), blk, 0, stream>>>(p2w, p2T, NHID_, NOUT_);

  // ---- edge weights for all 4 layers (one pass over easort) ----
  compute_w4_k<<<(E_+255)/256, blk, 0, stream>>>(easort, mu, sigma, wsrt4);

  const int MB = (N_ + 127)/128;  // 235
  const int MB64 = (N_ + 63)/64;  // 469

  // ---- 4 GMMConv + BN layers (t-formulation, 64-row BK=64 GEMM, stats fused) ----
  for (int l = 0; l < L_; l++){
    const bf16* hin = l ? (hlist + (size_t)(l-1)*N_*C_) : xb;
    aggregate_t_k<<<N_/4, blk, 0, stream>>>(hin, wsrt4 + (size_t)l*E_*K_, rowptr, srcsort, degf, tbuf);
    gmm_gemm64_k<<<dim3(MB64), blk, 0, stream>>>(
        tbuf, gGT + (size_t)l*C_*K_*C_, hin, rootT + (size_t)l*C_*C_,
        bias + (size_t)l*C_, hpre, bnstats + l*2*C_, N_);
    bn_apply_k<<<(N_*C_+255)/256, blk, 0, stream>>>(hpre, bnstats + l*2*C_, bng + (size_t)l*C_, bnb + (size_t)l*C_,
                                                    hlist + (size_t)l*N_*C_, (l < L_-1) ? 1 : 0);
  }

  // ---- bidirectional JK-LSTM over xs = [x, h1..h4] (T=5), both dirs per dispatch ----
  {
    const bf16 *hpf = nullptr, *hpb = nullptr;
    for (int s = 0; s < 5; s++){
      int tf = s, tb = 4 - s;
      const bf16* xtf = tf ? (hlist + (size_t)(tf-1)*N_*C_) : xb;
      const bf16* xtb = tb ? (hlist + (size_t)(tb-1)*N_*C_) : xb;
      bf16* hof = (s == 4) ? nullptr : ((s & 1) ? hBf : hAf);
      bf16* hob = (s == 4) ? nullptr : ((s & 1) ? hBb : hAb);
      lstm_step2_k<<<dim3(8, MB, 2), blk, 0, stream>>>(
          xtf, xtb, wihp, whhp, hpf, hpb, bsum, hof, hob, csf, csb,
          attw, alpha + (size_t)tf*N_, alpha + (size_t)tb*N_, N_);
      hpf = hof; hpb = hob;
    }
  }

  // ---- JK attention softmax + weighted sum + global mean pool ----
  jk_pool_k<<<N_, 128, 0, stream>>>(x, hlist, alpha, batch, hgraph, gcnt);
  pool_div_k<<<(B_*C_+255)/256, blk, 0, stream>>>(hgraph, gcnt, hgb);

  // ---- MLP head + LayerNorm ----
  gemm_bf16_k<1><<<dim3(NHID_/128, B_/128), blk, 0, stream>>>(
      hgb, p1T, C_, nullptr, nullptr, 0, p1b, z1b, B_, NHID_, 1);
  gemm_bf16_k<0><<<dim3(NOUT_/128, B_/128), blk, 0, stream>>>(
      z1b, p2T, NHID_, nullptr, nullptr, 0, p2b, outp, B_, NOUT_, 0);
  layernorm_k<<<B_, 256, 0, stream>>>(outp, lng, lnb);
}

// Round 14
// 1168.585 us; speedup vs baseline: 1.3170x; 1.0216x over previous
//
#include <hip/hip_runtime.h>
#include <hip/hip_bf16.h>
#include <math.h>

#define N_    30000
#define E_    480000
#define C_    128
#define K_    8
#define L_    4
#define H_    256
#define NHID_ 512
#define NOUT_ 256
#define B_    1024
#define SCAN_B 30   // ceil(N_/1024)

typedef __attribute__((ext_vector_type(8))) short short8;
typedef __attribute__((ext_vector_type(4))) float floatx4;
typedef __hip_bfloat16 bf16;

static inline size_t align256(size_t x){ return (x + 255) & ~(size_t)255; }

__device__ __forceinline__ void gload_lds16(const void* g, void* l){
  __builtin_amdgcn_global_load_lds((const __attribute__((address_space(1))) void*)g,
                                   (__attribute__((address_space(3))) void*)l, 16, 0, 0);
}
__device__ __forceinline__ float bf2f(short s){
  union { unsigned u; float f; } x; x.u = ((unsigned)(unsigned short)s) << 16; return x.f;
}
// fast sigmoid/tanh: v_exp-based, ~1e-5 rel err (negligible vs bf16 rounding)
__device__ __forceinline__ float sigm_f(float x){ return __builtin_amdgcn_rcpf(1.f + __expf(-x)); }
__device__ __forceinline__ float tanh_f(float x){ return 1.f - 2.f*__builtin_amdgcn_rcpf(1.f + __expf(2.f*x)); }

// ============================ CSR build ============================
__global__ void hist_k(const int* __restrict__ dst, int* __restrict__ cnt){
  int e = blockIdx.x*256 + threadIdx.x;
  if (e < E_) atomicAdd(&cnt[dst[e]], 1);
}

// scan + degf fused (cnt already in hand)
__global__ void scan1_k(const int* __restrict__ cnt, int* __restrict__ rowptr,
                        int* __restrict__ btot, float* __restrict__ degf){
  __shared__ int sh[1024];
  int i = blockIdx.x*1024 + (int)threadIdx.x;
  int v = (i < N_) ? cnt[i] : 0;
  if (i < N_) degf[i] = fmaxf((float)v, 1.0f);
  sh[threadIdx.x] = v;
  __syncthreads();
  for (int o = 1; o < 1024; o <<= 1){
    int t = (threadIdx.x >= (unsigned)o) ? sh[threadIdx.x - o] : 0;
    __syncthreads();
    sh[threadIdx.x] += t;
    __syncthreads();
  }
  if (i < N_) rowptr[i] = sh[threadIdx.x] - v;
  if (threadIdx.x == 1023) btot[blockIdx.x] = sh[1023];
}
__global__ void scan2_k(const int* __restrict__ btot, int* __restrict__ boff){
  if (threadIdx.x == 0){
    int s = 0;
    for (int b = 0; b < SCAN_B; b++){ boff[b] = s; s += btot[b]; }
    boff[SCAN_B] = s;
  }
}
__global__ void scan3_k(int* __restrict__ rowptr, const int* __restrict__ boff){
  int i = blockIdx.x*1024 + (int)threadIdx.x;
  if (i < N_) rowptr[i] += boff[blockIdx.x];
  if (i == N_-1) rowptr[N_] = boff[SCAN_B];
}

// also scatters edge_attr into CSR order (so compute_w needs no indirection)
__global__ void scatter_k(const int* __restrict__ src, const int* __restrict__ dst,
                          const float* __restrict__ ea,
                          const int* __restrict__ rowptr, int* __restrict__ fill,
                          int* __restrict__ srcsort, float* __restrict__ easort){
  int e = blockIdx.x*256 + threadIdx.x;
  if (e >= E_) return;
  int d = dst[e];
  int pos = rowptr[d] + atomicAdd(&fill[d], 1);
  srcsort[pos] = src[e];
  ((float2*)easort)[pos] = ((const float2*)ea)[e];
}

// ============================ casts ============================
__global__ void cast_k(const float* __restrict__ in, bf16* __restrict__ out, int n){
  int i = blockIdx.x*256 + threadIdx.x;
  if (i < n) out[i] = __float2bfloat16(in[i]);
}
// in: [batch][R][Cc] fp32 -> out: [batch][Cc][R] bf16 (N x K layout for GEMM B^T)
__global__ void tcast_k(const float* __restrict__ in, bf16* __restrict__ out, int R, int Cc){
  const float* ip = in + (size_t)blockIdx.y*R*Cc;
  bf16* op = out + (size_t)blockIdx.y*R*Cc;
  int i = blockIdx.x*256 + threadIdx.x;
  if (i >= R*Cc) return;
  int c = i / R, r = i - c*R;
  op[i] = __float2bfloat16(ip[(size_t)r*Cc + c]);
}
// g[l]: [C, K*C] -> gGT[l]: [c'][k*C+c] = g[c][k*C+c']   (B^T layout for t-GEMM)
__global__ void gtcast_k(const float* __restrict__ in, bf16* __restrict__ out){
  const float* ip = in + (size_t)blockIdx.y*C_*(K_*C_);
  bf16* op = out + (size_t)blockIdx.y*C_*(K_*C_);
  int i = blockIdx.x*256 + threadIdx.x;   // < 131072
  int co = i >> 10;
  int rem = i & 1023;
  int k = rem >> 7, c = rem & 127;
  op[i] = __float2bfloat16(ip[(size_t)c*(K_*C_) + k*C_ + co]);
}
// LSTM weights: permute gate rows so within each wave's 64 cols, nt==gate, lrow==channel.
// pi(r): gate=r>>8, j=r&255 -> (j>>5)*128 + ((j>>4)&1)*64 + gate*16 + (j&15)
__global__ void permcast_k(const float* __restrict__ in, bf16* __restrict__ out, int Kdim){
  const float* ip = in + (size_t)blockIdx.y*1024*Kdim;
  bf16* op = out + (size_t)blockIdx.y*1024*Kdim;
  int i = blockIdx.x*256 + threadIdx.x;
  if (i >= 1024*Kdim) return;
  int r = i / Kdim, k = i - r*Kdim;
  int gsel = r >> 8, jj = r & 255;
  int p = ((jj >> 5) << 7) + (((jj >> 4) & 1) << 6) + (gsel << 4) + (jj & 15);
  op[(size_t)p*Kdim + k] = __float2bfloat16(ip[i]);
}
__global__ void biassum_k(const float* __restrict__ bih, const float* __restrict__ bhh,
                          float* __restrict__ bs){
  int i = blockIdx.x*256 + threadIdx.x;  // < 2048, original gate-major order
  if (i < 2048) bs[i] = bih[i] + bhh[i];
}

// ============================ bf16 MFMA GEMM (generic, BK=32, xor-swizzled LDS) ============
// Staging slot c holds row=c>>2, chunk j=(c&3)^((c>>3)&3): coalesced 64B-contiguous global
// reads per row, and fragment reads at slot row*4+(lk^((row>>1)&3)) are 2 lanes/bank (free).
// C[M,Nn] = A1[M,K1] @ B1[Nn,K1]^T (+ A2[M,K2] @ B2[Nn,K2]^T) (+bias1) (relu)
template<int OUTBF16>
__global__ __launch_bounds__(256)
void gemm_bf16_k(const bf16* __restrict__ A1, const bf16* __restrict__ B1, int K1,
                 const bf16* __restrict__ A2, const bf16* __restrict__ B2, int K2,
                 const float* __restrict__ bias1,
                 void* __restrict__ Cout, int M, int Nn, int relu)
{
  __shared__ short As[128*32];
  __shared__ short Bs[128*32];
  const int tid  = threadIdx.x;
  const int wave = tid >> 6, lane = tid & 63;
  const int m0 = blockIdx.y*128, n0 = blockIdx.x*128;
  const int wm = (wave >> 1)*64, wn = (wave & 1)*64;
  const int lrow = lane & 15, lk = lane >> 4;
  floatx4 acc[4][4] = {};

  #pragma unroll
  for (int phase = 0; phase < 2; ++phase){
    const bf16* A = phase ? A2 : A1;
    const bf16* B = phase ? B2 : B1;
    const int   K = phase ? K2 : K1;
    if (A == nullptr) continue;
    for (int k0 = 0; k0 < K; k0 += 32){
      #pragma unroll
      for (int i = 0; i < 2; ++i){
        const int c    = i*256 + wave*64 + lane;
        const int row  = c >> 2;
        const int jsrc = (c & 3) ^ ((c >> 3) & 3);
        int ar = m0 + row; if (ar >= M) ar = M - 1;
        gload_lds16(A + (size_t)ar*K + k0 + jsrc*8,         As + (size_t)c*8);
        gload_lds16(B + (size_t)(n0 + row)*K + k0 + jsrc*8, Bs + (size_t)c*8);
      }
      __syncthreads();
      short8 af[4], bfr[4];
      #pragma unroll
      for (int t = 0; t < 4; ++t){
        const int ra = wm + t*16 + lrow;
        const int rb = wn + t*16 + lrow;
        af[t]  = *(const short8*)&As[(ra*4 + (lk ^ ((ra >> 1) & 3)))*8];
        bfr[t] = *(const short8*)&Bs[(rb*4 + (lk ^ ((rb >> 1) & 3)))*8];
      }
      #pragma unroll
      for (int mt = 0; mt < 4; ++mt)
        #pragma unroll
        for (int nt = 0; nt < 4; ++nt)
          acc[mt][nt] = __builtin_amdgcn_mfma_f32_16x16x32_bf16(af[mt], bfr[nt], acc[mt][nt], 0, 0, 0);
      __syncthreads();
    }
  }

  float* outf = (float*)Cout;
  bf16*  outb = (bf16*)Cout;
  #pragma unroll
  for (int nt = 0; nt < 4; ++nt){
    const int col = n0 + wn + nt*16 + lrow;
    float bv = bias1 ? bias1[col] : 0.f;
    #pragma unroll
    for (int mt = 0; mt < 4; ++mt){
      #pragma unroll
      for (int r = 0; r < 4; ++r){
        const int row = m0 + wm + mt*16 + lk*4 + r;   // C/D: col=lane&15, row=(lane>>4)*4+reg
        if (row >= M) continue;
        float v = acc[mt][nt][r] + bv;
        if (relu) v = fmaxf(v, 0.f);
        if (OUTBF16) outb[(size_t)row*Nn + col] = __float2bfloat16(v);
        else         outf[(size_t)row*Nn + col] = v;
      }
    }
  }
}

// ============================ GMM GEMM, 64-row tiles, BK=64, stats fused ============================
// hpre = t@G_stacked(K=1024) + h@root(K=128) + bias. 64x128 tile -> 469 blocks; BK=64 xor
// swizzle: slot c holds row=c>>3, chunk (c&7)^(row&7) -> contiguous 128B per row (coalesced),
// fragment reads 2 lanes/bank. Same k-order -> bit-identical. Stats fused.
__global__ __launch_bounds__(256)
void gmm_gemm64_k(const bf16* __restrict__ tbuf, const bf16* __restrict__ gGTl,
                  const bf16* __restrict__ hin, const bf16* __restrict__ rootTl,
                  const float* __restrict__ bias, float* __restrict__ outp,
                  float* __restrict__ stats, int M)
{
  __shared__ short As[64*64];    // 8 KB
  __shared__ short Bs[128*64];   // 16 KB
  __shared__ float colstat[256];
  const int tid  = threadIdx.x;
  const int wave = tid >> 6, lane = tid & 63;
  const int m0 = blockIdx.x*64;
  const int wn = wave*32;
  const int lrow = lane & 15, lk = lane >> 4;
  floatx4 acc[4][2] = {};
  colstat[tid] = 0.f;

  #pragma unroll
  for (int phase = 0; phase < 2; ++phase){
    const bf16* A  = phase ? hin    : tbuf;
    const bf16* B  = phase ? rootTl : gGTl;
    const int   ld = phase ? C_     : (K_*C_);
    const int   K  = phase ? C_     : (K_*C_);
    for (int k0 = 0; k0 < K; k0 += 64){
      #pragma unroll
      for (int i = 0; i < 6; ++i){
        const int t = i*256 + wave*64 + lane;
        if (t < 512){
          const int c = t, row = c >> 3, jsrc = (c & 7) ^ (row & 7);
          int ar = m0 + row; if (ar >= M) ar = M - 1;
          gload_lds16(A + (size_t)ar*ld + k0 + jsrc*8, As + (size_t)c*8);
        } else {
          const int c = t - 512, row = c >> 3, jsrc = (c & 7) ^ (row & 7);
          gload_lds16(B + (size_t)row*ld + k0 + jsrc*8, Bs + (size_t)c*8);
        }
      }
      __syncthreads();
      #pragma unroll
      for (int kk = 0; kk < 2; ++kk){
        short8 af[4], bfr[2];
        #pragma unroll
        for (int t = 0; t < 4; ++t){
          const int ra = t*16 + lrow;
          af[t] = *(const short8*)&As[(ra*8 + ((kk*4 + lk) ^ (ra & 7)))*8];
        }
        #pragma unroll
        for (int u = 0; u < 2; ++u){
          const int rb = wn + u*16 + lrow;
          bfr[u] = *(const short8*)&Bs[(rb*8 + ((kk*4 + lk) ^ (rb & 7)))*8];
        }
        #pragma unroll
        for (int mt = 0; mt < 4; ++mt)
          #pragma unroll
          for (int u = 0; u < 2; ++u)
            acc[mt][u] = __builtin_amdgcn_mfma_f32_16x16x32_bf16(af[mt], bfr[u], acc[mt][u], 0, 0, 0);
      }
      __syncthreads();
    }
  }

  #pragma unroll
  for (int u = 0; u < 2; ++u){
    const int col = wn + u*16 + lrow;
    const float bv = bias[col];
    float s = 0.f, s2 = 0.f;
    #pragma unroll
    for (int mt = 0; mt < 4; ++mt){
      #pragma unroll
      for (int r = 0; r < 4; ++r){
        const int row = m0 + mt*16 + lk*4 + r;
        if (row >= M) continue;
        float v = acc[mt][u][r] + bv;
        outp[(size_t)row*C_ + col] = v;
        s += v; s2 += v*v;
      }
    }
    s  += __shfl_down(s, 16);  s  += __shfl_down(s, 32);
    s2 += __shfl_down(s2, 16); s2 += __shfl_down(s2, 32);
    if (lane < 16){
      atomicAdd(&colstat[col], s);
      atomicAdd(&colstat[128 + col], s2);
    }
  }
  __syncthreads();
  if (tid < 128){
    atomicAdd(&stats[tid],       colstat[tid]);
    atomicAdd(&stats[128 + tid], colstat[128 + tid]);
  }
}

// ============================ fused LSTM step, both directions ============================
// r6/r10 grid (8 n-tiles fastest, 235 m-tiles, 2 dirs): 8 A-tile sharers temporally
// concurrent on 8 XCDs (max MLP). NEW: BK=64 with xor-swizzle — halves barrier drains
// 12->6 while keeping r10's exact global coalescing (each row sources one contiguous
// 128B, permuted within) and 2-lanes/bank fragment reads. Same k-order -> bit-identical.
// (r9's BK=64 regression was the chunk-major coalescing loss, not BK — counters showed
// same occupancy/FETCH as r10 yet 50% slower.) LDS 32 KB caps 5 blocks/CU > measured 2.5.
// Weights permuted so nt==gate, lrow==channel: pointwise LSTM in registers. c-state bf16.
// hpf/hpb==nullptr -> step 0 (h=c=0). hof==nullptr -> final step (h/c outputs never read).
__global__ __launch_bounds__(256)
void lstm_step2_k(const bf16* __restrict__ A1f, const bf16* __restrict__ A1b,
                  const bf16* __restrict__ wihp, const bf16* __restrict__ whhp,
                  const bf16* __restrict__ hpf, const bf16* __restrict__ hpb,
                  const float* __restrict__ bsum,   // [2][4][H] combined bias
                  bf16* __restrict__ hof, bf16* __restrict__ hob,
                  bf16* __restrict__ csf, bf16* __restrict__ csb,
                  const float* __restrict__ attw,   // [2][H]
                  float* __restrict__ alf, float* __restrict__ alb,
                  int M)
{
  __shared__ short As[128*64];   // 16 KB
  __shared__ short Bs[128*64];   // 16 KB
  const int dir = blockIdx.z;
  const bf16* A1 = dir ? A1b : A1f;
  const bf16* A2 = dir ? hpb : hpf;
  const bf16* B1 = wihp + (size_t)dir*4*H_*C_;
  const bf16* B2 = whhp + (size_t)dir*4*H_*H_;
  bf16* hout = dir ? hob : hof;
  bf16* cst  = dir ? csb : csf;
  float* alpha = dir ? alb : alf;
  const float* bsd = bsum + (size_t)dir*4*H_;
  const float* awd = attw + (size_t)dir*H_;

  const int tid  = threadIdx.x;
  const int wave = tid >> 6, lane = tid & 63;
  const int m0 = blockIdx.y*128, n0 = blockIdx.x*128;
  const int wm = (wave >> 1)*64, wn = (wave & 1)*64;
  const int lrow = lane & 15, lk = lane >> 4;
  floatx4 acc[4][4] = {};

  #pragma unroll
  for (int phase = 0; phase < 2; ++phase){
    const bf16* A = phase ? A2 : A1;
    const bf16* B = phase ? B2 : B1;
    const int   K = phase ? H_ : C_;
    if (A == nullptr) continue;
    for (int k0 = 0; k0 < K; k0 += 64){
      #pragma unroll
      for (int i = 0; i < 4; ++i){
        const int c    = i*256 + wave*64 + lane;      // slot 0..1023
        const int row  = c >> 3;
        const int jsrc = (c & 7) ^ (row & 7);
        int ar = m0 + row; if (ar >= M) ar = M - 1;
        gload_lds16(A + (size_t)ar*K + k0 + jsrc*8,         As + (size_t)c*8);
        gload_lds16(B + (size_t)(n0 + row)*K + k0 + jsrc*8, Bs + (size_t)c*8);
      }
      __syncthreads();
      #pragma unroll
      for (int kk = 0; kk < 2; ++kk){
        short8 af[4], bfr[4];
        #pragma unroll
        for (int t = 0; t < 4; ++t){
          const int ra = wm + t*16 + lrow;
          const int rb = wn + t*16 + lrow;
          af[t]  = *(const short8*)&As[(ra*8 + ((kk*4 + lk) ^ (ra & 7)))*8];
          bfr[t] = *(const short8*)&Bs[(rb*8 + ((kk*4 + lk) ^ (rb & 7)))*8];
        }
        #pragma unroll
        for (int mt = 0; mt < 4; ++mt)
          #pragma unroll
          for (int nt = 0; nt < 4; ++nt)
            acc[mt][nt] = __builtin_amdgcn_mfma_f32_16x16x32_bf16(af[mt], bfr[nt], acc[mt][nt], 0, 0, 0);
      }
      __syncthreads();
    }
  }

  // ---- register-resident pointwise: lane owns channel j, 16 rows; acc[mt][gate][r] ----
  const int j  = blockIdx.x*32 + (wave & 1)*16 + lrow;   // global channel in [0,H)
  const float bi = bsd[0*H_ + j], bff = bsd[1*H_ + j];
  const float bg = bsd[2*H_ + j], bo  = bsd[3*H_ + j];
  const float aw = awd[j];
  #pragma unroll
  for (int mt = 0; mt < 4; ++mt){
    #pragma unroll
    for (int r = 0; r < 4; ++r){
      const int row = m0 + wm + mt*16 + lk*4 + r;
      const bool ok = row < M;
      const size_t idx = (size_t)row*H_ + j;
      float co = 0.f;
      if (A2 && ok) co = __bfloat162float(cst[idx]);
      float ig = sigm_f(acc[mt][0][r] + bi);
      float fg = sigm_f(acc[mt][1][r] + bff);
      float gt = tanh_f(acc[mt][2][r] + bg);
      float og = sigm_f(acc[mt][3][r] + bo);
      float cv = fg*co + ig*gt;
      float hv = og*tanh_f(cv);
      if (ok && hout){                  // final step: h/c never read again -> skip stores
        cst[idx]  = __float2bfloat16(cv);
        hout[idx] = __float2bfloat16(hv);
      }
      float att = ok ? hv*aw : 0.f;
      att += __shfl_xor(att, 1);
      att += __shfl_xor(att, 2);
      att += __shfl_xor(att, 4);
      att += __shfl_xor(att, 8);
      if (lrow == 0 && ok) atomicAdd(&alpha[row], att);
    }
  }
}

// ============================ GMM layer pieces ============================
// edge weights for ALL 4 layers in one pass (easort read once), CSR order, bf16
__global__ void compute_w4_k(const float* __restrict__ easort, const float* __restrict__ mu,
                             const float* __restrict__ sigma, bf16* __restrict__ wsrt4)
{
  int e = blockIdx.x*256 + threadIdx.x;
  if (e >= E_) return;
  float2 a = ((const float2*)easort)[e];
  #pragma unroll
  for (int l = 0; l < L_; l++){
    short8 o;
    #pragma unroll
    for (int k = 0; k < 8; k++){
      float d0 = a.x - mu[l*16 + 2*k],  d1 = a.y - mu[l*16 + 2*k+1];
      float s0 = sigma[l*16 + 2*k],     s1 = sigma[l*16 + 2*k+1];
      float t = -0.5f*(d0*d0/(1e-15f + s0*s0) + d1*d1/(1e-15f + s1*s1));
      o[k] = __builtin_bit_cast(short, __float2bfloat16(expf(t)));
    }
    *(short8*)(wsrt4 + ((size_t)l*E_ + e)*8) = o;
  }
}

// t[d,k,:] = (1/deg_d) * sum_{e->d} w[e,k] * h[src_e,:]  -- wave per dst node.
__global__ __launch_bounds__(256)
void aggregate_t_k(const bf16* __restrict__ h, const bf16* __restrict__ wsrt,
                   const int* __restrict__ rowptr, const int* __restrict__ srcsort,
                   const float* __restrict__ degf, bf16* __restrict__ t)
{
  int node = blockIdx.x*4 + (threadIdx.x >> 6);
  int lane = threadIdx.x & 63;
  if (node >= N_) return;
  int p0 = rowptr[node], p1 = rowptr[node+1];
  float ax[8] = {}, ay[8] = {};
  for (int p = p0; p < p1; p++){
    int s = srcsort[p];
    short8 wv = *(const short8*)(wsrt + (size_t)p*8);
    float2 v = __bfloat1622float2(((const __hip_bfloat162*)(h + (size_t)s*C_))[lane]);
    #pragma unroll
    for (int k = 0; k < 8; k++){
      float wk = bf2f(wv[k]);
      ax[k] = fmaf(wk, v.x, ax[k]);
      ay[k] = fmaf(wk, v.y, ay[k]);
    }
  }
  float inv = 1.0f / degf[node];
  __hip_bfloat162* tp = (__hip_bfloat162*)(t + (size_t)node*(K_*C_));
  #pragma unroll
  for (int k = 0; k < 8; k++){
    __hip_bfloat162 o; o.x = __float2bfloat16(ax[k]*inv); o.y = __float2bfloat16(ay[k]*inv);
    tp[k*64 + lane] = o;
  }
}

__global__ void bn_apply_k(const float* __restrict__ hpre, const float* __restrict__ stats,
                           const float* __restrict__ gamma, const float* __restrict__ beta,
                           bf16* __restrict__ outp, int relu)
{
  int i = blockIdx.x*256 + threadIdx.x;
  if (i >= N_*C_) return;
  int c = i & 127;
  float mean = stats[c] * (1.0f/N_);
  float var  = stats[c+128] * (1.0f/N_) - mean*mean;
  float rstd = rsqrtf(var + 1e-5f);
  float v = (hpre[i] - mean)*rstd*gamma[c] + beta[c];
  if (relu) v = fmaxf(v, 0.f);
  outp[i] = __float2bfloat16(v);
}

// ============================ JK softmax + pooling ============================
__global__ void jk_pool_k(const float* __restrict__ x, const bf16* __restrict__ hlist,
                          const float* __restrict__ alpha, const int* __restrict__ batch,
                          float* __restrict__ hgraph, float* __restrict__ gcnt)
{
  int n = blockIdx.x, c = threadIdx.x;
  float a[5]; float mx = -1e30f;
  #pragma unroll
  for (int t = 0; t < 5; t++){ a[t] = alpha[(size_t)t*N_ + n]; mx = fmaxf(mx, a[t]); }
  float ssum = 0.f;
  #pragma unroll
  for (int t = 0; t < 5; t++){ a[t] = expf(a[t] - mx); ssum += a[t]; }
  float inv = 1.0f/ssum;
  float val = a[0]*inv*x[(size_t)n*C_ + c];
  #pragma unroll
  for (int t = 1; t < 5; t++)
    val = fmaf(a[t]*inv, __bfloat162float(hlist[((size_t)(t-1)*N_ + n)*C_ + c]), val);
  int bg = batch[n];
  atomicAdd(&hgraph[(size_t)bg*C_ + c], val);
  if (c == 0) atomicAdd(&gcnt[bg], 1.0f);
}

__global__ void pool_div_k(const float* __restrict__ hg, const float* __restrict__ gcnt,
                           bf16* __restrict__ hgb){
  int i = blockIdx.x*256 + threadIdx.x;
  if (i < B_*C_) hgb[i] = __float2bfloat16(hg[i] / fmaxf(gcnt[i >> 7], 1.0f));
}

// ============================ final LayerNorm ============================
__global__ __launch_bounds__(256)
void layernorm_k(float* __restrict__ z, const float* __restrict__ g, const float* __restrict__ b){
  int row = blockIdx.x, j = threadIdx.x;
  float v = z[(size_t)row*NOUT_ + j];
  float s = v, s2 = v*v;
  #pragma unroll
  for (int o = 32; o; o >>= 1){ s += __shfl_down(s, o); s2 += __shfl_down(s2, o); }
  __shared__ float sh[8];
  int w = j >> 6;
  if ((j & 63) == 0){ sh[w] = s; sh[4+w] = s2; }
  __syncthreads();
  float st  = sh[0] + sh[1] + sh[2] + sh[3];
  float st2 = sh[4] + sh[5] + sh[6] + sh[7];
  float mean = st * (1.0f/NOUT_);
  float var  = st2 * (1.0f/NOUT_) - mean*mean;
  float rstd = rsqrtf(var + 1e-5f);
  z[(size_t)row*NOUT_ + j] = (v - mean)*rstd*g[j] + b[j];
}

// ============================ launch ============================
extern "C" void kernel_launch(void* const* d_in, const int* in_sizes, int n_in,
                              void* d_out, int out_size, void* d_ws, size_t ws_size,
                              hipStream_t stream)
{
  (void)in_sizes; (void)n_in; (void)out_size; (void)ws_size;
  const float* x     = (const float*)d_in[0];
  const int*   eidx  = (const int*)  d_in[1];
  const float* eattr = (const float*)d_in[2];
  const int*   batch = (const int*)  d_in[3];
  const float* g     = (const float*)d_in[4];
  const float* root  = (const float*)d_in[5];
  const float* bias  = (const float*)d_in[6];
  const float* mu    = (const float*)d_in[7];
  const float* sigma = (const float*)d_in[8];
  const float* bng   = (const float*)d_in[9];
  const float* bnb   = (const float*)d_in[10];
  const float* w_ih  = (const float*)d_in[11];
  const float* w_hh  = (const float*)d_in[12];
  const float* b_ih  = (const float*)d_in[13];
  const float* b_hh  = (const float*)d_in[14];
  const float* attw  = (const float*)d_in[15];
  // d_in[16] = att_b: softmax-shift-invariant, unused
  const float* p1w   = (const float*)d_in[17];
  const float* p1b   = (const float*)d_in[18];
  const float* p2w   = (const float*)d_in[19];
  const float* p2b   = (const float*)d_in[20];
  const float* lng   = (const float*)d_in[21];
  const float* lnb   = (const float*)d_in[22];
  float* outp = (float*)d_out;

  const int* src = eidx;
  const int* dst = eidx + E_;

  // ---- workspace carve (~205 MB) ----
  size_t off = 0;
  char* wsb = (char*)d_ws;
  auto carve = [&](size_t bytes)->void*{ void* p = wsb + off; off = align256(off + bytes); return p; };
  bf16*  hlist  = (bf16*) carve((size_t)L_*N_*C_*2);        // 30.7 MB  h_list[1..4] bf16
  void*  big    =         carve((size_t)N_*(K_*C_)*2);      // 61.4 MB: t bf16
  void*  uni    =         carve((size_t)6*N_*H_*2 + 256);   // GMM: wsrt4(30.7)+hpre(15.4) | LSTM: 2x(hA,hB,c) 92MB
  bf16*  xb     = (bf16*) carve((size_t)N_*C_*2);           // x in bf16
  // ---- contiguous zero-init region (single memset) ----
  size_t zstart = off;
  int* cnt      = (int*)  carve((size_t)N_*4);
  int* fill     = (int*)  carve((size_t)N_*4);
  float* bnstats= (float*)carve((size_t)L_*2*C_*4);
  float* hgraph = (float*)carve((size_t)B_*C_*4);
  float* gcnt   = (float*)carve((size_t)B_*4);
  float* alpha  = (float*)carve((size_t)(L_+1)*N_*4);
  size_t zend = off;
  // ---- rest ----
  bf16*  hgb    = (bf16*) carve((size_t)B_*C_*2);
  bf16*  z1b    = (bf16*) carve((size_t)B_*NHID_*2);
  float* degf   = (float*)carve((size_t)N_*4);
  int* rowptr   = (int*)  carve((size_t)(N_+1)*4);
  int* srcsort  = (int*)  carve((size_t)E_*4);
  float* easort = (float*)carve((size_t)E_*2*4);
  int* btot     = (int*)  carve((size_t)(SCAN_B+1)*4);
  int* boff     = (int*)  carve((size_t)(SCAN_B+1)*4);
  // bf16 weights
  bf16* gGT   = (bf16*)carve((size_t)L_*C_*(K_*C_)*2);      // [L][c'][k*C+c] for t-GEMM
  bf16* rootT = (bf16*)carve((size_t)L_*C_*C_*2);           // [L][C, C]
  bf16* wihp  = (bf16*)carve((size_t)2*4*H_*C_*2);          // [2][1024][128] gate-permuted
  bf16* whhp  = (bf16*)carve((size_t)2*4*H_*H_*2);          // [2][1024][256] gate-permuted
  float* bsum = (float*)carve((size_t)2*4*H_*4);            // b_ih+b_hh, original order
  bf16* p1T   = (bf16*)carve((size_t)NHID_*C_*2);
  bf16* p2T   = (bf16*)carve((size_t)NOUT_*NHID_*2);

  // union aliases (GMM phase vs LSTM phase)
  bf16*  wsrt4  = (bf16*)uni;                                // [4][E,8] bf16  30.7 MB
  float* hpre   = (float*)((char*)uni + (size_t)L_*E_*K_*2); // [N,C] fp32 15.4 MB
  bf16*  hAf    = (bf16*)uni;                                // per-dir h ping/pong + c, each [N,H] bf16
  bf16*  hAb    = hAf + (size_t)N_*H_;
  bf16*  hBf    = hAb + (size_t)N_*H_;
  bf16*  hBb    = hBf + (size_t)N_*H_;
  bf16*  csf    = hBb + (size_t)N_*H_;
  bf16*  csb    = csf + (size_t)N_*H_;
  bf16*  tbuf   = (bf16*)big;                                // [N,K*C] bf16

  // ---- zero-init: one contiguous memset (ws is poisoned every call) ----
  hipMemsetAsync(wsb + zstart, 0, zend - zstart, stream);

  const dim3 blk(256);

  // ---- CSR build ----
  hist_k  <<<(E_+255)/256, 256, 0, stream>>>(dst, cnt);
  scan1_k <<<SCAN_B, 1024, 0, stream>>>(cnt, rowptr, btot, degf);
  scan2_k <<<1, 64, 0, stream>>>(btot, boff);
  scan3_k <<<SCAN_B, 1024, 0, stream>>>(rowptr, boff);
  scatter_k<<<(E_+255)/256, 256, 0, stream>>>(src, dst, eattr, rowptr, fill, srcsort, easort);

  // ---- weight/activation casts ----
  cast_k <<<(N_*C_+255)/256, blk, 0, stream>>>(x, xb, N_*C_);
  gtcast_k<<<dim3((C_*K_*C_)/256, L_), blk, 0, stream>>>(g, gGT);
  tcast_k<<<dim3((C_*C_+255)/256,   L_), blk, 0, stream>>>(root, rootT, C_,   C_);
  permcast_k<<<dim3((1024*C_+255)/256, 2), blk, 0, stream>>>(w_ih, wihp, C_);
  permcast_k<<<dim3((1024*H_+255)/256, 2), blk, 0, stream>>>(w_hh, whhp, H_);
  biassum_k<<<8, blk, 0, stream>>>(b_ih, b_hh, bsum);
  tcast_k<<<dim3((C_*NHID_+255)/256, 1), blk, 0, stream>>>(p1w, p1T, C_,    NHID_);
  tcast_k<<<dim3((NHID_*NOUT_+255)/256,1), blk, 0, stream>>>(p2w, p2T, NHID_, NOUT_);

  // ---- edge weights for all 4 layers (one pass over easort) ----
  compute_w4_k<<<(E_+255)/256, blk, 0, stream>>>(easort, mu, sigma, wsrt4);

  const int MB = (N_ + 127)/128;  // 235
  const int MB64 = (N_ + 63)/64;  // 469

  // ---- 4 GMMConv + BN layers (t-formulation, 64-row BK=64 GEMM, stats fused) ----
  for (int l = 0; l < L_; l++){
    const bf16* hin = l ? (hlist + (size_t)(l-1)*N_*C_) : xb;
    aggregate_t_k<<<N_/4, blk, 0, stream>>>(hin, wsrt4 + (size_t)l*E_*K_, rowptr, srcsort, degf, tbuf);
    gmm_gemm64_k<<<dim3(MB64), blk, 0, stream>>>(
        tbuf, gGT + (size_t)l*C_*K_*C_, hin, rootT + (size_t)l*C_*C_,
        bias + (size_t)l*C_, hpre, bnstats + l*2*C_, N_);
    bn_apply_k<<<(N_*C_+255)/256, blk, 0, stream>>>(hpre, bnstats + l*2*C_, bng + (size_t)l*C_, bnb + (size_t)l*C_,
                                                    hlist + (size_t)l*N_*C_, (l < L_-1) ? 1 : 0);
  }

  // ---- bidirectional JK-LSTM over xs = [x, h1..h4] (T=5), both dirs per dispatch ----
  {
    const bf16 *hpf = nullptr, *hpb = nullptr;
    for (int s = 0; s < 5; s++){
      int tf = s, tb = 4 - s;
      const bf16* xtf = tf ? (hlist + (size_t)(tf-1)*N_*C_) : xb;
      const bf16* xtb = tb ? (hlist + (size_t)(tb-1)*N_*C_) : xb;
      bf16* hof = (s == 4) ? nullptr : ((s & 1) ? hBf : hAf);
      bf16* hob = (s == 4) ? nullptr : ((s & 1) ? hBb : hAb);
      lstm_step2_k<<<dim3(8, MB, 2), blk, 0, stream>>>(
          xtf, xtb, wihp, whhp, hpf, hpb, bsum, hof, hob, csf, csb,
          attw, alpha + (size_t)tf*N_, alpha + (size_t)tb*N_, N_);
      hpf = hof; hpb = hob;
    }
  }

  // ---- JK attention softmax + weighted sum + global mean pool ----
  jk_pool_k<<<N_, 128, 0, stream>>>(x, hlist, alpha, batch, hgraph, gcnt);
  pool_div_k<<<(B_*C_+255)/256, blk, 0, stream>>>(hgraph, gcnt, hgb);

  // ---- MLP head + LayerNorm ----
  gemm_bf16_k<1><<<dim3(NHID_/128, B_/128), blk, 0, stream>>>(
      hgb, p1T, C_, nullptr, nullptr, 0, p1b, z1b, B_, NHID_, 1);
  gemm_bf16_k<0><<<dim3(NOUT_/128, B_/128), blk, 0, stream>>>(
      z1b, p2T, NHID_, nullptr, nullptr, 0, p2b, outp, B_, NOUT_, 0);
  layernorm_k<<<B_, 256, 0, stream>>>(outp, lng, lnb);
}

// Round 15
// 1159.085 us; speedup vs baseline: 1.3278x; 1.0082x over previous
//
#include <hip/hip_runtime.h>
#include <hip/hip_bf16.h>
#include <math.h>

#define N_    30000
#define E_    480000
#define C_    128
#define K_    8
#define L_    4
#define H_    256
#define NHID_ 512
#define NOUT_ 256
#define B_    1024
#define SCAN_B 30   // ceil(N_/1024)

typedef __attribute__((ext_vector_type(8))) short short8;
typedef __attribute__((ext_vector_type(4))) float floatx4;
typedef __hip_bfloat16 bf16;

static inline size_t align256(size_t x){ return (x + 255) & ~(size_t)255; }

__device__ __forceinline__ void gload_lds16(const void* g, void* l){
  __builtin_amdgcn_global_load_lds((const __attribute__((address_space(1))) void*)g,
                                   (__attribute__((address_space(3))) void*)l, 16, 0, 0);
}
__device__ __forceinline__ float bf2f(short s){
  union { unsigned u; float f; } x; x.u = ((unsigned)(unsigned short)s) << 16; return x.f;
}
// fast sigmoid/tanh: v_exp-based, ~1e-5 rel err (negligible vs bf16 rounding)
__device__ __forceinline__ float sigm_f(float x){ return __builtin_amdgcn_rcpf(1.f + __expf(-x)); }
__device__ __forceinline__ float tanh_f(float x){ return 1.f - 2.f*__builtin_amdgcn_rcpf(1.f + __expf(2.f*x)); }

// ============================ CSR build ============================
__global__ void hist_k(const int* __restrict__ dst, int* __restrict__ cnt){
  int e = blockIdx.x*256 + threadIdx.x;
  if (e < E_) atomicAdd(&cnt[dst[e]], 1);
}

// scan + degf fused (cnt already in hand)
__global__ void scan1_k(const int* __restrict__ cnt, int* __restrict__ rowptr,
                        int* __restrict__ btot, float* __restrict__ degf){
  __shared__ int sh[1024];
  int i = blockIdx.x*1024 + (int)threadIdx.x;
  int v = (i < N_) ? cnt[i] : 0;
  if (i < N_) degf[i] = fmaxf((float)v, 1.0f);
  sh[threadIdx.x] = v;
  __syncthreads();
  for (int o = 1; o < 1024; o <<= 1){
    int t = (threadIdx.x >= (unsigned)o) ? sh[threadIdx.x - o] : 0;
    __syncthreads();
    sh[threadIdx.x] += t;
    __syncthreads();
  }
  if (i < N_) rowptr[i] = sh[threadIdx.x] - v;
  if (threadIdx.x == 1023) btot[blockIdx.x] = sh[1023];
}
__global__ void scan2_k(const int* __restrict__ btot, int* __restrict__ boff){
  if (threadIdx.x == 0){
    int s = 0;
    for (int b = 0; b < SCAN_B; b++){ boff[b] = s; s += btot[b]; }
    boff[SCAN_B] = s;
  }
}
__global__ void scan3_k(int* __restrict__ rowptr, const int* __restrict__ boff){
  int i = blockIdx.x*1024 + (int)threadIdx.x;
  if (i < N_) rowptr[i] += boff[blockIdx.x];
  if (i == N_-1) rowptr[N_] = boff[SCAN_B];
}

// also scatters edge_attr into CSR order (so compute_w needs no indirection)
__global__ void scatter_k(const int* __restrict__ src, const int* __restrict__ dst,
                          const float* __restrict__ ea,
                          const int* __restrict__ rowptr, int* __restrict__ fill,
                          int* __restrict__ srcsort, float* __restrict__ easort){
  int e = blockIdx.x*256 + threadIdx.x;
  if (e >= E_) return;
  int d = dst[e];
  int pos = rowptr[d] + atomicAdd(&fill[d], 1);
  srcsort[pos] = src[e];
  ((float2*)easort)[pos] = ((const float2*)ea)[e];
}

// ============================ casts ============================
__global__ void cast_k(const float* __restrict__ in, bf16* __restrict__ out, int n){
  int i = blockIdx.x*256 + threadIdx.x;
  if (i < n) out[i] = __float2bfloat16(in[i]);
}
// in: [batch][R][Cc] fp32 -> out: [batch][Cc][R] bf16 (N x K layout for GEMM B^T)
__global__ void tcast_k(const float* __restrict__ in, bf16* __restrict__ out, int R, int Cc){
  const float* ip = in + (size_t)blockIdx.y*R*Cc;
  bf16* op = out + (size_t)blockIdx.y*R*Cc;
  int i = blockIdx.x*256 + threadIdx.x;
  if (i >= R*Cc) return;
  int c = i / R, r = i - c*R;
  op[i] = __float2bfloat16(ip[(size_t)r*Cc + c]);
}
// g[l]: [C, K*C] -> gGT[l]: [c'][k*C+c] = g[c][k*C+c']   (B^T layout for t-GEMM)
__global__ void gtcast_k(const float* __restrict__ in, bf16* __restrict__ out){
  const float* ip = in + (size_t)blockIdx.y*C_*(K_*C_);
  bf16* op = out + (size_t)blockIdx.y*C_*(K_*C_);
  int i = blockIdx.x*256 + threadIdx.x;   // < 131072
  int co = i >> 10;
  int rem = i & 1023;
  int k = rem >> 7, c = rem & 127;
  op[i] = __float2bfloat16(ip[(size_t)c*(K_*C_) + k*C_ + co]);
}
// LSTM weights: permute gate rows so within each wave's 64 cols, nt==gate, lrow==channel.
// pi(r): gate=r>>8, j=r&255 -> (j>>5)*128 + ((j>>4)&1)*64 + gate*16 + (j&15)
__global__ void permcast_k(const float* __restrict__ in, bf16* __restrict__ out, int Kdim){
  const float* ip = in + (size_t)blockIdx.y*1024*Kdim;
  bf16* op = out + (size_t)blockIdx.y*1024*Kdim;
  int i = blockIdx.x*256 + threadIdx.x;
  if (i >= 1024*Kdim) return;
  int r = i / Kdim, k = i - r*Kdim;
  int gsel = r >> 8, jj = r & 255;
  int p = ((jj >> 5) << 7) + (((jj >> 4) & 1) << 6) + (gsel << 4) + (jj & 15);
  op[(size_t)p*Kdim + k] = __float2bfloat16(ip[i]);
}
__global__ void biassum_k(const float* __restrict__ bih, const float* __restrict__ bhh,
                          float* __restrict__ bs){
  int i = blockIdx.x*256 + threadIdx.x;  // < 2048, original gate-major order
  if (i < 2048) bs[i] = bih[i] + bhh[i];
}

// ============================ bf16 MFMA GEMM (generic, BK=32, xor-swizzled LDS) ============
// Staging slot c holds row=c>>2, chunk j=(c&3)^((c>>3)&3): coalesced 64B-contiguous global
// reads per row, and fragment reads at slot row*4+(lk^((row>>1)&3)) are 2 lanes/bank (free).
// C[M,Nn] = A1[M,K1] @ B1[Nn,K1]^T (+ A2[M,K2] @ B2[Nn,K2]^T) (+bias1) (relu)
template<int OUTBF16>
__global__ __launch_bounds__(256)
void gemm_bf16_k(const bf16* __restrict__ A1, const bf16* __restrict__ B1, int K1,
                 const bf16* __restrict__ A2, const bf16* __restrict__ B2, int K2,
                 const float* __restrict__ bias1,
                 void* __restrict__ Cout, int M, int Nn, int relu)
{
  __shared__ short As[128*32];
  __shared__ short Bs[128*32];
  const int tid  = threadIdx.x;
  const int wave = tid >> 6, lane = tid & 63;
  const int m0 = blockIdx.y*128, n0 = blockIdx.x*128;
  const int wm = (wave >> 1)*64, wn = (wave & 1)*64;
  const int lrow = lane & 15, lk = lane >> 4;
  floatx4 acc[4][4] = {};

  #pragma unroll
  for (int phase = 0; phase < 2; ++phase){
    const bf16* A = phase ? A2 : A1;
    const bf16* B = phase ? B2 : B1;
    const int   K = phase ? K2 : K1;
    if (A == nullptr) continue;
    for (int k0 = 0; k0 < K; k0 += 32){
      #pragma unroll
      for (int i = 0; i < 2; ++i){
        const int c    = i*256 + wave*64 + lane;
        const int row  = c >> 2;
        const int jsrc = (c & 3) ^ ((c >> 3) & 3);
        int ar = m0 + row; if (ar >= M) ar = M - 1;
        gload_lds16(A + (size_t)ar*K + k0 + jsrc*8,         As + (size_t)c*8);
        gload_lds16(B + (size_t)(n0 + row)*K + k0 + jsrc*8, Bs + (size_t)c*8);
      }
      __syncthreads();
      short8 af[4], bfr[4];
      #pragma unroll
      for (int t = 0; t < 4; ++t){
        const int ra = wm + t*16 + lrow;
        const int rb = wn + t*16 + lrow;
        af[t]  = *(const short8*)&As[(ra*4 + (lk ^ ((ra >> 1) & 3)))*8];
        bfr[t] = *(const short8*)&Bs[(rb*4 + (lk ^ ((rb >> 1) & 3)))*8];
      }
      #pragma unroll
      for (int mt = 0; mt < 4; ++mt)
        #pragma unroll
        for (int nt = 0; nt < 4; ++nt)
          acc[mt][nt] = __builtin_amdgcn_mfma_f32_16x16x32_bf16(af[mt], bfr[nt], acc[mt][nt], 0, 0, 0);
      __syncthreads();
    }
  }

  float* outf = (float*)Cout;
  bf16*  outb = (bf16*)Cout;
  #pragma unroll
  for (int nt = 0; nt < 4; ++nt){
    const int col = n0 + wn + nt*16 + lrow;
    float bv = bias1 ? bias1[col] : 0.f;
    #pragma unroll
    for (int mt = 0; mt < 4; ++mt){
      #pragma unroll
      for (int r = 0; r < 4; ++r){
        const int row = m0 + wm + mt*16 + lk*4 + r;   // C/D: col=lane&15, row=(lane>>4)*4+reg
        if (row >= M) continue;
        float v = acc[mt][nt][r] + bv;
        if (relu) v = fmaxf(v, 0.f);
        if (OUTBF16) outb[(size_t)row*Nn + col] = __float2bfloat16(v);
        else         outf[(size_t)row*Nn + col] = v;
      }
    }
  }
}

// ============================ GMM GEMM, 64-row tiles, BK=128, stats fused ============================
// hpre = t@G_stacked(K=1024) + h@root(K=128) + bias. 64x128 tile -> 469 blocks (~1.8/CU,
// under-subscribed so LDS growth costs nothing). BK=128 halves drains 18 -> 10 vs BK=64
// (the r12/r14-validated lever for latency-exposed grids). Swizzle: slot c holds row=c>>4,
// chunk (c&15)^(row&15) -> each row sources one contiguous 256B (coalesced); fragment reads
// perm (kk*4+lk)^(ra&15) land exactly 2 lanes/bank. Same k-order -> GEMM bit-identical.
// Output bf16 (stats accumulated fp32 pre-rounding); per-column sum/sumsq fused into stats.
__global__ __launch_bounds__(256)
void gmm_gemm128_k(const bf16* __restrict__ tbuf, const bf16* __restrict__ gGTl,
                   const bf16* __restrict__ hin, const bf16* __restrict__ rootTl,
                   const float* __restrict__ bias, bf16* __restrict__ outp,
                   float* __restrict__ stats, int M)
{
  __shared__ short As[64*128];    // 16 KB
  __shared__ short Bs[128*128];   // 32 KB
  __shared__ float colstat[256];
  const int tid  = threadIdx.x;
  const int wave = tid >> 6, lane = tid & 63;
  const int m0 = blockIdx.x*64;
  const int wn = wave*32;
  const int lrow = lane & 15, lk = lane >> 4;
  floatx4 acc[4][2] = {};
  colstat[tid] = 0.f;

  #pragma unroll
  for (int phase = 0; phase < 2; ++phase){
    const bf16* A  = phase ? hin    : tbuf;
    const bf16* B  = phase ? rootTl : gGTl;
    const int   ld = phase ? C_     : (K_*C_);
    const int   K  = phase ? C_     : (K_*C_);
    for (int k0 = 0; k0 < K; k0 += 128){
      // 1024 A-chunks + 2048 B-chunks = 3072; 12 iters x 4 waves x 64 lanes; wave-uniform split.
      #pragma unroll
      for (int i = 0; i < 12; ++i){
        const int t = i*256 + wave*64 + lane;
        if (t < 1024){
          const int c = t, row = c >> 4, jsrc = (c & 15) ^ (row & 15);
          int ar = m0 + row; if (ar >= M) ar = M - 1;
          gload_lds16(A + (size_t)ar*ld + k0 + jsrc*8, As + (size_t)c*8);
        } else {
          const int c = t - 1024, row = c >> 4, jsrc = (c & 15) ^ (row & 15);
          gload_lds16(B + (size_t)row*ld + k0 + jsrc*8, Bs + (size_t)c*8);
        }
      }
      __syncthreads();
      #pragma unroll
      for (int kk = 0; kk < 4; ++kk){
        short8 af[4], bfr[2];
        #pragma unroll
        for (int t = 0; t < 4; ++t){
          const int ra = t*16 + lrow;
          af[t] = *(const short8*)&As[(ra*16 + ((kk*4 + lk) ^ (ra & 15)))*8];
        }
        #pragma unroll
        for (int u = 0; u < 2; ++u){
          const int rb = wn + u*16 + lrow;
          bfr[u] = *(const short8*)&Bs[(rb*16 + ((kk*4 + lk) ^ (rb & 15)))*8];
        }
        #pragma unroll
        for (int mt = 0; mt < 4; ++mt)
          #pragma unroll
          for (int u = 0; u < 2; ++u)
            acc[mt][u] = __builtin_amdgcn_mfma_f32_16x16x32_bf16(af[mt], bfr[u], acc[mt][u], 0, 0, 0);
      }
      __syncthreads();
    }
  }

  #pragma unroll
  for (int u = 0; u < 2; ++u){
    const int col = wn + u*16 + lrow;
    const float bv = bias[col];
    float s = 0.f, s2 = 0.f;
    #pragma unroll
    for (int mt = 0; mt < 4; ++mt){
      #pragma unroll
      for (int r = 0; r < 4; ++r){
        const int row = m0 + mt*16 + lk*4 + r;
        if (row >= M) continue;
        float v = acc[mt][u][r] + bv;
        outp[(size_t)row*C_ + col] = __float2bfloat16(v);
        s += v; s2 += v*v;
      }
    }
    s  += __shfl_down(s, 16);  s  += __shfl_down(s, 32);
    s2 += __shfl_down(s2, 16); s2 += __shfl_down(s2, 32);
    if (lane < 16){
      atomicAdd(&colstat[col], s);
      atomicAdd(&colstat[128 + col], s2);
    }
  }
  __syncthreads();
  if (tid < 128){
    atomicAdd(&stats[tid],       colstat[tid]);
    atomicAdd(&stats[128 + tid], colstat[128 + tid]);
  }
}

// ============================ fused LSTM step, both directions ============================
// FROZEN r14 config: grid (8 n-tiles fastest, 235 m-tiles, 2 dirs) = 8 concurrent A-sharers
// on 8 XCDs (max MLP); BK=64 xor-swizzle (coalesced + conflict-free, 6 drains/step).
// Weights permuted so nt==gate, lrow==channel: pointwise LSTM in registers. c-state bf16.
// hpf/hpb==nullptr -> step 0 (h=c=0). hof==nullptr -> final step (h/c outputs never read).
__global__ __launch_bounds__(256)
void lstm_step2_k(const bf16* __restrict__ A1f, const bf16* __restrict__ A1b,
                  const bf16* __restrict__ wihp, const bf16* __restrict__ whhp,
                  const bf16* __restrict__ hpf, const bf16* __restrict__ hpb,
                  const float* __restrict__ bsum,   // [2][4][H] combined bias
                  bf16* __restrict__ hof, bf16* __restrict__ hob,
                  bf16* __restrict__ csf, bf16* __restrict__ csb,
                  const float* __restrict__ attw,   // [2][H]
                  float* __restrict__ alf, float* __restrict__ alb,
                  int M)
{
  __shared__ short As[128*64];   // 16 KB
  __shared__ short Bs[128*64];   // 16 KB
  const int dir = blockIdx.z;
  const bf16* A1 = dir ? A1b : A1f;
  const bf16* A2 = dir ? hpb : hpf;
  const bf16* B1 = wihp + (size_t)dir*4*H_*C_;
  const bf16* B2 = whhp + (size_t)dir*4*H_*H_;
  bf16* hout = dir ? hob : hof;
  bf16* cst  = dir ? csb : csf;
  float* alpha = dir ? alb : alf;
  const float* bsd = bsum + (size_t)dir*4*H_;
  const float* awd = attw + (size_t)dir*H_;

  const int tid  = threadIdx.x;
  const int wave = tid >> 6, lane = tid & 63;
  const int m0 = blockIdx.y*128, n0 = blockIdx.x*128;
  const int wm = (wave >> 1)*64, wn = (wave & 1)*64;
  const int lrow = lane & 15, lk = lane >> 4;
  floatx4 acc[4][4] = {};

  #pragma unroll
  for (int phase = 0; phase < 2; ++phase){
    const bf16* A = phase ? A2 : A1;
    const bf16* B = phase ? B2 : B1;
    const int   K = phase ? H_ : C_;
    if (A == nullptr) continue;
    for (int k0 = 0; k0 < K; k0 += 64){
      #pragma unroll
      for (int i = 0; i < 4; ++i){
        const int c    = i*256 + wave*64 + lane;      // slot 0..1023
        const int row  = c >> 3;
        const int jsrc = (c & 7) ^ (row & 7);
        int ar = m0 + row; if (ar >= M) ar = M - 1;
        gload_lds16(A + (size_t)ar*K + k0 + jsrc*8,         As + (size_t)c*8);
        gload_lds16(B + (size_t)(n0 + row)*K + k0 + jsrc*8, Bs + (size_t)c*8);
      }
      __syncthreads();
      #pragma unroll
      for (int kk = 0; kk < 2; ++kk){
        short8 af[4], bfr[4];
        #pragma unroll
        for (int t = 0; t < 4; ++t){
          const int ra = wm + t*16 + lrow;
          const int rb = wn + t*16 + lrow;
          af[t]  = *(const short8*)&As[(ra*8 + ((kk*4 + lk) ^ (ra & 7)))*8];
          bfr[t] = *(const short8*)&Bs[(rb*8 + ((kk*4 + lk) ^ (rb & 7)))*8];
        }
        #pragma unroll
        for (int mt = 0; mt < 4; ++mt)
          #pragma unroll
          for (int nt = 0; nt < 4; ++nt)
            acc[mt][nt] = __builtin_amdgcn_mfma_f32_16x16x32_bf16(af[mt], bfr[nt], acc[mt][nt], 0, 0, 0);
      }
      __syncthreads();
    }
  }

  // ---- register-resident pointwise: lane owns channel j, 16 rows; acc[mt][gate][r] ----
  const int j  = blockIdx.x*32 + (wave & 1)*16 + lrow;   // global channel in [0,H)
  const float bi = bsd[0*H_ + j], bff = bsd[1*H_ + j];
  const float bg = bsd[2*H_ + j], bo  = bsd[3*H_ + j];
  const float aw = awd[j];
  #pragma unroll
  for (int mt = 0; mt < 4; ++mt){
    #pragma unroll
    for (int r = 0; r < 4; ++r){
      const int row = m0 + wm + mt*16 + lk*4 + r;
      const bool ok = row < M;
      const size_t idx = (size_t)row*H_ + j;
      float co = 0.f;
      if (A2 && ok) co = __bfloat162float(cst[idx]);
      float ig = sigm_f(acc[mt][0][r] + bi);
      float fg = sigm_f(acc[mt][1][r] + bff);
      float gt = tanh_f(acc[mt][2][r] + bg);
      float og = sigm_f(acc[mt][3][r] + bo);
      float cv = fg*co + ig*gt;
      float hv = og*tanh_f(cv);
      if (ok && hout){                  // final step: h/c never read again -> skip stores
        cst[idx]  = __float2bfloat16(cv);
        hout[idx] = __float2bfloat16(hv);
      }
      float att = ok ? hv*aw : 0.f;
      att += __shfl_xor(att, 1);
      att += __shfl_xor(att, 2);
      att += __shfl_xor(att, 4);
      att += __shfl_xor(att, 8);
      if (lrow == 0 && ok) atomicAdd(&alpha[row], att);
    }
  }
}

// ============================ GMM layer pieces ============================
// edge weights for ALL 4 layers in one pass (easort read once), CSR order, bf16
__global__ void compute_w4_k(const float* __restrict__ easort, const float* __restrict__ mu,
                             const float* __restrict__ sigma, bf16* __restrict__ wsrt4)
{
  int e = blockIdx.x*256 + threadIdx.x;
  if (e >= E_) return;
  float2 a = ((const float2*)easort)[e];
  #pragma unroll
  for (int l = 0; l < L_; l++){
    short8 o;
    #pragma unroll
    for (int k = 0; k < 8; k++){
      float d0 = a.x - mu[l*16 + 2*k],  d1 = a.y - mu[l*16 + 2*k+1];
      float s0 = sigma[l*16 + 2*k],     s1 = sigma[l*16 + 2*k+1];
      float t = -0.5f*(d0*d0/(1e-15f + s0*s0) + d1*d1/(1e-15f + s1*s1));
      o[k] = __builtin_bit_cast(short, __float2bfloat16(expf(t)));
    }
    *(short8*)(wsrt4 + ((size_t)l*E_ + e)*8) = o;
  }
}

// t[d,k,:] = (1/deg_d) * sum_{e->d} w[e,k] * h[src_e,:]  -- wave per dst node.
__global__ __launch_bounds__(256)
void aggregate_t_k(const bf16* __restrict__ h, const bf16* __restrict__ wsrt,
                   const int* __restrict__ rowptr, const int* __restrict__ srcsort,
                   const float* __restrict__ degf, bf16* __restrict__ t)
{
  int node = blockIdx.x*4 + (threadIdx.x >> 6);
  int lane = threadIdx.x & 63;
  if (node >= N_) return;
  int p0 = rowptr[node], p1 = rowptr[node+1];
  float ax[8] = {}, ay[8] = {};
  for (int p = p0; p < p1; p++){
    int s = srcsort[p];
    short8 wv = *(const short8*)(wsrt + (size_t)p*8);
    float2 v = __bfloat1622float2(((const __hip_bfloat162*)(h + (size_t)s*C_))[lane]);
    #pragma unroll
    for (int k = 0; k < 8; k++){
      float wk = bf2f(wv[k]);
      ax[k] = fmaf(wk, v.x, ax[k]);
      ay[k] = fmaf(wk, v.y, ay[k]);
    }
  }
  float inv = 1.0f / degf[node];
  __hip_bfloat162* tp = (__hip_bfloat162*)(t + (size_t)node*(K_*C_));
  #pragma unroll
  for (int k = 0; k < 8; k++){
    __hip_bfloat162 o; o.x = __float2bfloat16(ax[k]*inv); o.y = __float2bfloat16(ay[k]*inv);
    tp[k*64 + lane] = o;
  }
}

__global__ void bn_apply_k(const bf16* __restrict__ hpre, const float* __restrict__ stats,
                           const float* __restrict__ gamma, const float* __restrict__ beta,
                           bf16* __restrict__ outp, int relu)
{
  int i = blockIdx.x*256 + threadIdx.x;
  if (i >= N_*C_) return;
  int c = i & 127;
  float mean = stats[c] * (1.0f/N_);
  float var  = stats[c+128] * (1.0f/N_) - mean*mean;
  float rstd = rsqrtf(var + 1e-5f);
  float v = (__bfloat162float(hpre[i]) - mean)*rstd*gamma[c] + beta[c];
  if (relu) v = fmaxf(v, 0.f);
  outp[i] = __float2bfloat16(v);
}

// ============================ JK softmax + pooling ============================
__global__ void jk_pool_k(const float* __restrict__ x, const bf16* __restrict__ hlist,
                          const float* __restrict__ alpha, const int* __restrict__ batch,
                          float* __restrict__ hgraph, float* __restrict__ gcnt)
{
  int n = blockIdx.x, c = threadIdx.x;
  float a[5]; float mx = -1e30f;
  #pragma unroll
  for (int t = 0; t < 5; t++){ a[t] = alpha[(size_t)t*N_ + n]; mx = fmaxf(mx, a[t]); }
  float ssum = 0.f;
  #pragma unroll
  for (int t = 0; t < 5; t++){ a[t] = expf(a[t] - mx); ssum += a[t]; }
  float inv = 1.0f/ssum;
  float val = a[0]*inv*x[(size_t)n*C_ + c];
  #pragma unroll
  for (int t = 1; t < 5; t++)
    val = fmaf(a[t]*inv, __bfloat162float(hlist[((size_t)(t-1)*N_ + n)*C_ + c]), val);
  int bg = batch[n];
  atomicAdd(&hgraph[(size_t)bg*C_ + c], val);
  if (c == 0) atomicAdd(&gcnt[bg], 1.0f);
}

__global__ void pool_div_k(const float* __restrict__ hg, const float* __restrict__ gcnt,
                           bf16* __restrict__ hgb){
  int i = blockIdx.x*256 + threadIdx.x;
  if (i < B_*C_) hgb[i] = __float2bfloat16(hg[i] / fmaxf(gcnt[i >> 7], 1.0f));
}

// ============================ final LayerNorm ============================
__global__ __launch_bounds__(256)
void layernorm_k(float* __restrict__ z, const float* __restrict__ g, const float* __restrict__ b){
  int row = blockIdx.x, j = threadIdx.x;
  float v = z[(size_t)row*NOUT_ + j];
  float s = v, s2 = v*v;
  #pragma unroll
  for (int o = 32; o; o >>= 1){ s += __shfl_down(s, o); s2 += __shfl_down(s2, o); }
  __shared__ float sh[8];
  int w = j >> 6;
  if ((j & 63) == 0){ sh[w] = s; sh[4+w] = s2; }
  __syncthreads();
  float st  = sh[0] + sh[1] + sh[2] + sh[3];
  float st2 = sh[4] + sh[5] + sh[6] + sh[7];
  float mean = st * (1.0f/NOUT_);
  float var  = st2 * (1.0f/NOUT_) - mean*mean;
  float rstd = rsqrtf(var + 1e-5f);
  z[(size_t)row*NOUT_ + j] = (v - mean)*rstd*g[j] + b[j];
}

// ============================ launch ============================
extern "C" void kernel_launch(void* const* d_in, const int* in_sizes, int n_in,
                              void* d_out, int out_size, void* d_ws, size_t ws_size,
                              hipStream_t stream)
{
  (void)in_sizes; (void)n_in; (void)out_size; (void)ws_size;
  const float* x     = (const float*)d_in[0];
  const int*   eidx  = (const int*)  d_in[1];
  const float* eattr = (const float*)d_in[2];
  const int*   batch = (const int*)  d_in[3];
  const float* g     = (const float*)d_in[4];
  const float* root  = (const float*)d_in[5];
  const float* bias  = (const float*)d_in[6];
  const float* mu    = (const float*)d_in[7];
  const float* sigma = (const float*)d_in[8];
  const float* bng   = (const float*)d_in[9];
  const float* bnb   = (const float*)d_in[10];
  const float* w_ih  = (const float*)d_in[11];
  const float* w_hh  = (const float*)d_in[12];
  const float* b_ih  = (const float*)d_in[13];
  const float* b_hh  = (const float*)d_in[14];
  const float* attw  = (const float*)d_in[15];
  // d_in[16] = att_b: softmax-shift-invariant, unused
  const float* p1w   = (const float*)d_in[17];
  const float* p1b   = (const float*)d_in[18];
  const float* p2w   = (const float*)d_in[19];
  const float* p2b   = (const float*)d_in[20];
  const float* lng   = (const float*)d_in[21];
  const float* lnb   = (const float*)d_in[22];
  float* outp = (float*)d_out;

  const int* src = eidx;
  const int* dst = eidx + E_;

  // ---- workspace carve (~205 MB) ----
  size_t off = 0;
  char* wsb = (char*)d_ws;
  auto carve = [&](size_t bytes)->void*{ void* p = wsb + off; off = align256(off + bytes); return p; };
  bf16*  hlist  = (bf16*) carve((size_t)L_*N_*C_*2);        // 30.7 MB  h_list[1..4] bf16
  void*  big    =         carve((size_t)N_*(K_*C_)*2);      // 61.4 MB: t bf16
  void*  uni    =         carve((size_t)6*N_*H_*2 + 256);   // GMM: wsrt4(30.7)+hpre(7.7) | LSTM: 2x(hA,hB,c) 92MB
  bf16*  xb     = (bf16*) carve((size_t)N_*C_*2);           // x in bf16
  // ---- contiguous zero-init region (single memset) ----
  size_t zstart = off;
  int* cnt      = (int*)  carve((size_t)N_*4);
  int* fill     = (int*)  carve((size_t)N_*4);
  float* bnstats= (float*)carve((size_t)L_*2*C_*4);
  float* hgraph = (float*)carve((size_t)B_*C_*4);
  float* gcnt   = (float*)carve((size_t)B_*4);
  float* alpha  = (float*)carve((size_t)(L_+1)*N_*4);
  size_t zend = off;
  // ---- rest ----
  bf16*  hgb    = (bf16*) carve((size_t)B_*C_*2);
  bf16*  z1b    = (bf16*) carve((size_t)B_*NHID_*2);
  float* degf   = (float*)carve((size_t)N_*4);
  int* rowptr   = (int*)  carve((size_t)(N_+1)*4);
  int* srcsort  = (int*)  carve((size_t)E_*4);
  float* easort = (float*)carve((size_t)E_*2*4);
  int* btot     = (int*)  carve((size_t)(SCAN_B+1)*4);
  int* boff     = (int*)  carve((size_t)(SCAN_B+1)*4);
  // bf16 weights
  bf16* gGT   = (bf16*)carve((size_t)L_*C_*(K_*C_)*2);      // [L][c'][k*C+c] for t-GEMM
  bf16* rootT = (bf16*)carve((size_t)L_*C_*C_*2);           // [L][C, C]
  bf16* wihp  = (bf16*)carve((size_t)2*4*H_*C_*2);          // [2][1024][128] gate-permuted
  bf16* whhp  = (bf16*)carve((size_t)2*4*H_*H_*2);          // [2][1024][256] gate-permuted
  float* bsum = (float*)carve((size_t)2*4*H_*4);            // b_ih+b_hh, original order
  bf16* p1T   = (bf16*)carve((size_t)NHID_*C_*2);
  bf16* p2T   = (bf16*)carve((size_t)NOUT_*NHID_*2);

  // union aliases (GMM phase vs LSTM phase)
  bf16*  wsrt4  = (bf16*)uni;                                // [4][E,8] bf16  30.7 MB
  bf16*  hpre   = (bf16*)((char*)uni + (size_t)L_*E_*K_*2);  // [N,C] bf16 7.7 MB
  bf16*  hAf    = (bf16*)uni;                                // per-dir h ping/pong + c, each [N,H] bf16
  bf16*  hAb    = hAf + (size_t)N_*H_;
  bf16*  hBf    = hAb + (size_t)N_*H_;
  bf16*  hBb    = hBf + (size_t)N_*H_;
  bf16*  csf    = hBb + (size_t)N_*H_;
  bf16*  csb    = csf + (size_t)N_*H_;
  bf16*  tbuf   = (bf16*)big;                                // [N,K*C] bf16

  // ---- zero-init: one contiguous memset (ws is poisoned every call) ----
  hipMemsetAsync(wsb + zstart, 0, zend - zstart, stream);

  const dim3 blk(256);

  // ---- CSR build ----
  hist_k  <<<(E_+255)/256, 256, 0, stream>>>(dst, cnt);
  scan1_k <<<SCAN_B, 1024, 0, stream>>>(cnt, rowptr, btot, degf);
  scan2_k <<<1, 64, 0, stream>>>(btot, boff);
  scan3_k <<<SCAN_B, 1024, 0, stream>>>(rowptr, boff);
  scatter_k<<<(E_+255)/256, 256, 0, stream>>>(src, dst, eattr, rowptr, fill, srcsort, easort);

  // ---- weight/activation casts ----
  cast_k <<<(N_*C_+255)/256, blk, 0, stream>>>(x, xb, N_*C_);
  gtcast_k<<<dim3((C_*K_*C_)/256, L_), blk, 0, stream>>>(g, gGT);
  tcast_k<<<dim3((C_*C_+255)/256,   L_), blk, 0, stream>>>(root, rootT, C_,   C_);
  permcast_k<<<dim3((1024*C_+255)/256, 2), blk, 0, stream>>>(w_ih, wihp, C_);
  permcast_k<<<dim3((1024*H_+255)/256, 2), blk, 0, stream>>>(w_hh, whhp, H_);
  biassum_k<<<8, blk, 0, stream>>>(b_ih, b_hh, bsum);
  tcast_k<<<dim3((C_*NHID_+255)/256, 1), blk, 0, stream>>>(p1w, p1T, C_,    NHID_);
  tcast_k<<<dim3((NHID_*NOUT_+255)/256,1), blk, 0, stream>>>(p2w, p2T, NHID_, NOUT_);

  // ---- edge weights for all 4 layers (one pass over easort) ----
  compute_w4_k<<<(E_+255)/256, blk, 0, stream>>>(easort, mu, sigma, wsrt4);

  const int MB = (N_ + 127)/128;  // 235
  const int MB64 = (N_ + 63)/64;  // 469

  // ---- 4 GMMConv + BN layers (t-formulation, 64-row BK=128 GEMM, stats fused) ----
  for (int l = 0; l < L_; l++){
    const bf16* hin = l ? (hlist + (size_t)(l-1)*N_*C_) : xb;
    aggregate_t_k<<<N_/4, blk, 0, stream>>>(hin, wsrt4 + (size_t)l*E_*K_, rowptr, srcsort, degf, tbuf);
    gmm_gemm128_k<<<dim3(MB64), blk, 0, stream>>>(
        tbuf, gGT + (size_t)l*C_*K_*C_, hin, rootT + (size_t)l*C_*C_,
        bias + (size_t)l*C_, hpre, bnstats + l*2*C_, N_);
    bn_apply_k<<<(N_*C_+255)/256, blk, 0, stream>>>(hpre, bnstats + l*2*C_, bng + (size_t)l*C_, bnb + (size_t)l*C_,
                                                    hlist + (size_t)l*N_*C_, (l < L_-1) ? 1 : 0);
  }

  // ---- bidirectional JK-LSTM over xs = [x, h1..h4] (T=5), both dirs per dispatch ----
  {
    const bf16 *hpf = nullptr, *hpb = nullptr;
    for (int s = 0; s < 5; s++){
      int tf = s, tb = 4 - s;
      const bf16* xtf = tf ? (hlist + (size_t)(tf-1)*N_*C_) : xb;
      const bf16* xtb = tb ? (hlist + (size_t)(tb-1)*N_*C_) : xb;
      bf16* hof = (s == 4) ? nullptr : ((s & 1) ? hBf : hAf);
      bf16* hob = (s == 4) ? nullptr : ((s & 1) ? hBb : hAb);
      lstm_step2_k<<<dim3(8, MB, 2), blk, 0, stream>>>(
          xtf, xtb, wihp, whhp, hpf, hpb, bsum, hof, hob, csf, csb,
          attw, alpha + (size_t)tf*N_, alpha + (size_t)tb*N_, N_);
      hpf = hof; hpb = hob;
    }
  }

  // ---- JK attention softmax + weighted sum + global mean pool ----
  jk_pool_k<<<N_, 128, 0, stream>>>(x, hlist, alpha, batch, hgraph, gcnt);
  pool_div_k<<<(B_*C_+255)/256, blk, 0, stream>>>(hgraph, gcnt, hgb);

  // ---- MLP head + LayerNorm ----
  gemm_bf16_k<1><<<dim3(NHID_/128, B_/128), blk, 0, stream>>>(
      hgb, p1T, C_, nullptr, nullptr, 0, p1b, z1b, B_, NHID_, 1);
  gemm_bf16_k<0><<<dim3(NOUT_/128, B_/128), blk, 0, stream>>>(
      z1b, p2T, NHID_, nullptr, nullptr, 0, p2b, outp, B_, NOUT_, 0);
  layernorm_k<<<B_, 256, 0, stream>>>(outp, lng, lnb);
}